// Round 13
// baseline (370.571 us; speedup 1.0000x reference)
//
#include <hip/hip_runtime.h>
#include <hip/hip_fp16.h>
#include <math.h>

#define B_TOT 512
#define CQKV  256
#define CIN   128
#define HLEN  128

static constexpr float F_QR = 0.3f, F_KR = 0.3f, F_SV = 0.5f, F_SVE = 0.3f;
static constexpr float EPS = 1e-5f;

typedef __attribute__((ext_vector_type(8))) short short8v;
typedef __attribute__((ext_vector_type(8))) _Float16 half8v;
typedef __attribute__((ext_vector_type(2))) _Float16 half2v;
typedef __attribute__((ext_vector_type(4))) float float4v;

#if __has_builtin(__builtin_amdgcn_fdot2)
#define HAVE_FDOT2 1
#endif

__device__ __forceinline__ unsigned short f2bf(float f) {
    unsigned u = __float_as_uint(f);
    unsigned r = u + 0x7fffu + ((u >> 16) & 1u);
    return (unsigned short)(r >> 16);
}
__device__ __forceinline__ unsigned short f2h(float f) {
    return __half_as_ushort(__float2half(f));
}

// ---------------------------------------------------------------------------
// Kernel 1 (MFMA): qkv GEMM + fused per-channel raw stats.
// qkv stored f16 (zero extra score error: k_attn rounded to f16 anyway).
// ---------------------------------------------------------------------------
__global__ __launch_bounds__(256, 3) void k_qkv(const float* __restrict__ x,
                                                const float* __restrict__ w,
                                                unsigned short* __restrict__ qkv,
                                                double* __restrict__ accA) {
    __shared__ unsigned short As[64][136];
    __shared__ unsigned short Xs[256][64];
    __shared__ float wsum[64][2];
    int bid = blockIdx.x;
    int n   = bid >> 7;
    int sub = bid & 127;
    int mt  = sub >> 2;
    int ot  = sub & 3;
    int m0  = mt << 8;
    int o0  = ot << 6;
    int t   = threadIdx.x;

    if (t < 64) { wsum[t][0] = 0.f; wsum[t][1] = 0.f; }

#pragma unroll
    for (int it = 0; it < 8; ++it) {
        int idx = it * 256 + t;
        int o = idx >> 5, c4 = (idx & 31) << 2;
        float4 wv = *(const float4*)(w + (size_t)(o0 + o) * CIN + c4);
        As[o][c4 + 0] = f2bf(wv.x);
        As[o][c4 + 1] = f2bf(wv.y);
        As[o][c4 + 2] = f2bf(wv.z);
        As[o][c4 + 3] = f2bf(wv.w);
    }

    const float* xn = x + (size_t)n * CIN * 8192 + m0;

    int wv_ = t >> 6, l = t & 63;
    int lr = l & 15, lh = l >> 4;
    int mw = wv_ << 6;

    float4v acc[4][4];
#pragma unroll
    for (int a = 0; a < 4; ++a)
#pragma unroll
        for (int b2 = 0; b2 < 4; ++b2) acc[a][b2] = (float4v){0.f, 0.f, 0.f, 0.f};

    for (int s = 0; s < 2; ++s) {
        int c0 = s << 6;
        __syncthreads();
#pragma unroll
        for (int it = 0; it < 16; ++it) {
            int c  = (it << 2) + (t >> 6);
            int m4 = (t & 63) << 2;
            float4 xv = *(const float4*)(xn + (size_t)(c0 + c) * 8192 + m4);
            float vals[4] = {xv.x, xv.y, xv.z, xv.w};
#pragma unroll
            for (int j = 0; j < 4; ++j) {
                int m = m4 + j;
                int cs = (((c >> 3) ^ ((m >> 2) & 7)) << 3) | (c & 7);
                Xs[m][cs] = f2bf(vals[j]);
            }
        }
        __syncthreads();
#pragma unroll
        for (int ks = 0; ks < 2; ++ks) {
            short8v af[4], bf[4];
#pragma unroll
            for (int a = 0; a < 4; ++a)
                af[a] = *(const short8v*)&As[a * 16 + lr][c0 + ks * 32 + lh * 8];
#pragma unroll
            for (int b2 = 0; b2 < 4; ++b2) {
                int m  = mw + b2 * 16 + lr;
                int cb = (ks * 4 + lh) ^ ((m >> 2) & 7);
                bf[b2] = *(const short8v*)&Xs[m][cb << 3];
            }
#pragma unroll
            for (int a = 0; a < 4; ++a)
#pragma unroll
                for (int b2 = 0; b2 < 4; ++b2)
                    acc[a][b2] = __builtin_amdgcn_mfma_f32_16x16x32_bf16(
                        af[a], bf[b2], acc[a][b2], 0, 0, 0);
        }
    }

#pragma unroll
    for (int a = 0; a < 4; ++a) {
#pragma unroll
        for (int b2 = 0; b2 < 4; ++b2) {
            int m  = m0 + mw + b2 * 16 + lr;
            int bb = n * 64 + (m >> 7);
            int h  = m & 127;
#pragma unroll
            for (int r = 0; r < 4; ++r) {
                int o = o0 + a * 16 + lh * 4 + r;
                qkv[((size_t)bb * CQKV + o) * HLEN + h] = f2h(acc[a][b2][r]);
            }
        }
    }

#pragma unroll
    for (int a = 0; a < 4; ++a) {
#pragma unroll
        for (int r = 0; r < 4; ++r) {
            float s = 0.f, ss = 0.f;
#pragma unroll
            for (int b2 = 0; b2 < 4; ++b2) {
                float v = acc[a][b2][r];
                s += v; ss += v * v;
            }
#pragma unroll
            for (int off = 1; off < 16; off <<= 1) {
                s  += __shfl_xor(s, off);
                ss += __shfl_xor(ss, off);
            }
            if (lr == 0) {
                int ol = a * 16 + lh * 4 + r;
                atomicAdd(&wsum[ol][0], s);
                atomicAdd(&wsum[ol][1], ss);
            }
        }
    }
    __syncthreads();
    if (t < 64) {
        atomicAdd(&accA[(size_t)(o0 + t) * 2 + 0], (double)wsum[t][0]);
        atomicAdd(&accA[(size_t)(o0 + t) * 2 + 1], (double)wsum[t][1]);
    }
}

__global__ void k_finA(const double* __restrict__ accA,
                       const float* __restrict__ g1, const float* __restrict__ g2,
                       const float* __restrict__ b2,
                       float* __restrict__ scaleA, float* __restrict__ shiftA) {
    int o = threadIdx.x;
    double cnt  = 65536.0;
    double mean = accA[o * 2] / cnt;
    double var  = accA[o * 2 + 1] / cnt - mean * mean;
    float r1 = rsqrtf((float)var + EPS);
    float v2 = g1[o] * g1[o] * (float)var * r1 * r1;
    float sc = g1[o] * g2[o] * r1 * rsqrtf(v2 + EPS);
    scaleA[o] = sc;
    shiftA[o] = b2[o] - (float)mean * sc;
}

__global__ void k_finF(const double* __restrict__ accF,
                       const float* __restrict__ go, const float* __restrict__ bo,
                       float* __restrict__ scaleF, float* __restrict__ shiftF) {
    int o = threadIdx.x;
    double cnt  = 65536.0;
    double mean = accF[o * 2] / cnt;
    double var  = accF[o * 2 + 1] / cnt - mean * mean;
    float sc = go[o] * rsqrtf((float)var + EPS);
    scaleF[o] = sc;
    shiftF[o] = bo[o] - (float)mean * sc;
}

// ---------------------------------------------------------------------------
// Tables for analytic score stats (f32, for k_gram).
// ---------------------------------------------------------------------------
__global__ __launch_bounds__(128) void k_tables(const float* __restrict__ rel,
                                                float* __restrict__ Rq, float* __restrict__ Rk,
                                                float* __restrict__ TqT, float* __restrict__ TkT) {
    int bid = blockIdx.x;      // 0..127
    int i = threadIdx.x;       // 0..127
    int p = bid & 63;
    int c = p >> 3, c2 = p & 7;
    const float* ra = (bid < 64) ? (rel + c * 255)  : (rel + (8 + c) * 255);
    const float* rb = (bid < 64) ? (rel + c2 * 255) : (rel + (8 + c2) * 255);
    float tacc = 0.f;
    for (int kk = 0; kk < 128; ++kk) tacc = fmaf(ra[i + kk], rb[i + kk], tacc);
    if (bid < 64) TqT[i * 64 + p] = tacc; else TkT[i * 64 + p] = tacc;
    if (c2 == 0) {
        float racc = 0.f;
        for (int kk = 0; kk < 128; ++kk) racc += ra[i + kk];
        if (bid < 64) Rq[c * 128 + i] = racc; else Rk[c * 128 + i] = racc;
    }
}

// ---------------------------------------------------------------------------
// Analytic score stats per (b,g) — 256 threads; qkv is f16.
// ---------------------------------------------------------------------------
__global__ __launch_bounds__(256) void k_gram(const unsigned short* __restrict__ qkv,
                                              const float* __restrict__ scaleA,
                                              const float* __restrict__ shiftA,
                                              const float* __restrict__ Rq,
                                              const float* __restrict__ Rk,
                                              const float* __restrict__ TqT,
                                              const float* __restrict__ TkT,
                                              double* __restrict__ accS) {
    __shared__ float qs[8][132], ks[8][132];
    __shared__ float redA[4][64][4];
    __shared__ float redB[2][18];
    __shared__ float redC[3];
    int blk = blockIdx.x, b = blk >> 3, g = blk & 7;
    int t = threadIdx.x;
    for (int idx = t; idx < 2048; idx += 256) {
        int cc = idx >> 7, h = idx & 127, o = g * 32 + cc;
        float raw = __half2float(__ushort_as_half(qkv[((size_t)b * CQKV + o) * HLEN + h]));
        float v = raw * scaleA[o] + shiftA[o];
        if (cc < 8) qs[cc][h] = v; else ks[cc - 8][h] = v;
    }
    __syncthreads();
    int lane = t & 63, wv = t >> 6;
    int c = lane >> 3, c2 = lane & 7;
    float gq = 0, gk = 0, tq = 0, tk = 0;
#pragma unroll 4
    for (int ii = 0; ii < 32; ++ii) {
        int i = wv * 32 + ii;
        float a = qs[c][i] * qs[c2][i];
        float e = ks[c][i] * ks[c2][i];
        gq += a; gk += e;
        tq = fmaf(a, TqT[i * 64 + lane], tq);
        tk = fmaf(e, TkT[i * 64 + lane], tk);
    }
    redA[wv][lane][0] = gq; redA[wv][lane][1] = gk;
    redA[wv][lane][2] = tq; redA[wv][lane][3] = tk;

    if (t < 128) {
        int h = t;
        float sqr = 0, skr = 0;
        float sq8l[8], sk8l[8];
#pragma unroll
        for (int c3 = 0; c3 < 8; ++c3) {
            float q0 = qs[c3][h], k0 = ks[c3][h];
            sq8l[c3] = q0; sk8l[c3] = k0;
            sqr = fmaf(q0, Rq[c3 * 128 + h], sqr);
            skr = fmaf(k0, Rk[c3 * 128 + h], skr);
        }
#pragma unroll
        for (int off = 1; off < 64; off <<= 1) {
            sqr += __shfl_xor(sqr, off);
            skr += __shfl_xor(skr, off);
#pragma unroll
            for (int c3 = 0; c3 < 8; ++c3) {
                sq8l[c3] += __shfl_xor(sq8l[c3], off);
                sk8l[c3] += __shfl_xor(sk8l[c3], off);
            }
        }
        if (lane == 0) {
            redB[wv][0] = sqr; redB[wv][1] = skr;
#pragma unroll
            for (int c3 = 0; c3 < 8; ++c3) {
                redB[wv][2 + c3]  = sq8l[c3];
                redB[wv][10 + c3] = sk8l[c3];
            }
        }
    }
    __syncthreads();
    if (t < 64) {
        float Gq = redA[0][t][0] + redA[1][t][0] + redA[2][t][0] + redA[3][t][0];
        float Gk = redA[0][t][1] + redA[1][t][1] + redA[2][t][1] + redA[3][t][1];
        float Tq = redA[0][t][2] + redA[1][t][2] + redA[2][t][2] + redA[3][t][2];
        float Tk = redA[0][t][3] + redA[1][t][3] + redA[2][t][3] + redA[3][t][3];
        float ssqk = Gq * Gk;
#pragma unroll
        for (int off = 1; off < 64; off <<= 1) {
            ssqk += __shfl_xor(ssqk, off);
            Tq   += __shfl_xor(Tq, off);
            Tk   += __shfl_xor(Tk, off);
        }
        if (t == 0) { redC[0] = ssqk; redC[1] = Tq; redC[2] = Tk; }
    }
    __syncthreads();
    if (t == 0) {
        float sqr = redB[0][0] + redB[1][0];
        float skr = redB[0][1] + redB[1][1];
        float sqk = 0;
#pragma unroll
        for (int c3 = 0; c3 < 8; ++c3)
            sqk += (redB[0][2 + c3] + redB[1][2 + c3]) * (redB[0][10 + c3] + redB[1][10 + c3]);
        atomicAdd(&accS[g * 2 + 0], (double)sqk);
        atomicAdd(&accS[g * 2 + 1], (double)redC[0]);
        atomicAdd(&accS[(8 + g) * 2 + 0], (double)(F_QR * sqr));
        atomicAdd(&accS[(8 + g) * 2 + 1], (double)(F_QR * F_QR * redC[1]));
        atomicAdd(&accS[(16 + g) * 2 + 0], (double)(F_KR * skr));
        atomicAdd(&accS[(16 + g) * 2 + 1], (double)(F_KR * F_KR * redC[2]));
    }
}

__global__ void k_sfin(const double* __restrict__ accS,
                       const float* __restrict__ gs, const float* __restrict__ bs,
                       float* __restrict__ scaleS, float* __restrict__ shiftS) {
    int c = threadIdx.x;
    if (c < 24) {
        double cnt  = 512.0 * 128.0 * 128.0;
        double mean = accS[c * 2] / cnt;
        double var  = accS[c * 2 + 1] / cnt - mean * mean;
        float sc = gs[c] * rsqrtf((float)var + EPS);
        scaleS[c] = sc;
        shiftS[c] = bs[c] - (float)mean * sc;
    }
}

// ---------------------------------------------------------------------------
// Attention — fragment-native (round-12) + f16 qkv/so + 6 blocks/CU.
// ---------------------------------------------------------------------------
__global__ __launch_bounds__(256, 6) void k_attn(const unsigned short* __restrict__ qkv,
                                                 const float* __restrict__ scaleA,
                                                 const float* __restrict__ shiftA,
                                                 const float* __restrict__ rel,
                                                 const float* __restrict__ scaleS,
                                                 const float* __restrict__ shiftS,
                                                 unsigned short* __restrict__ so,
                                                 double* __restrict__ accF) {
    __shared__ unsigned short qT[128][8];
    __shared__ unsigned short kF[128][8];
    __shared__ unsigned short vB[16][136];
    __shared__ unsigned short rqT[255][8];
    __shared__ unsigned short rkT[255][8];
    __shared__ unsigned short rvA[255][8];
    __shared__ unsigned short rvB[255][8];
    __shared__ float accL[32][2];
    int blk = blockIdx.x, b = blk >> 3, g = blk & 7;
    int t = threadIdx.x;
    if (t < 32) { accL[t][0] = 0.f; accL[t][1] = 0.f; }

    // ---- staging: qkv (f16) via uint2, affine in half2 domain ----
#pragma unroll
    for (int it = 0; it < 4; ++it) {
        int idx = it * 256 + t;
        int cc = idx >> 5;
        int h4 = (idx & 31) << 2;
        int o = g * 32 + cc;
        uint2 v4 = *(const uint2*)(qkv + ((size_t)b * CQKV + o) * HLEN + h4);
        __half2 sc2 = __float2half2_rn(scaleA[o]);
        __half2 sh2 = __float2half2_rn(shiftA[o]);
        __half2 va = __hfma2(*(__half2*)&v4.x, sc2, sh2);
        __half2 vb2 = __hfma2(*(__half2*)&v4.y, sc2, sh2);
        unsigned ua = *(unsigned*)&va, ub = *(unsigned*)&vb2;
        if (cc < 8) {
            qT[h4][cc]     = (unsigned short)(ua & 0xffff);
            qT[h4 + 1][cc] = (unsigned short)(ua >> 16);
            qT[h4 + 2][cc] = (unsigned short)(ub & 0xffff);
            qT[h4 + 3][cc] = (unsigned short)(ub >> 16);
        } else if (cc < 16) {
            kF[h4][cc - 8]     = (unsigned short)(ua & 0xffff);
            kF[h4 + 1][cc - 8] = (unsigned short)(ua >> 16);
            kF[h4 + 2][cc - 8] = (unsigned short)(ub & 0xffff);
            kF[h4 + 3][cc - 8] = (unsigned short)(ub >> 16);
        } else {
            uint2 pk; pk.x = ua; pk.y = ub;
            *(uint2*)&vB[cc - 16][h4] = pk;
        }
    }
    // ---- staging: rel via float4 ----
#pragma unroll
    for (int it = 0; it < 8; ++it) {
        int idx = it * 256 + t;
        if (idx < 2040) {
            float4 v = *(const float4*)(rel + (size_t)idx * 4);
            float vv[4] = {v.x, v.y, v.z, v.w};
#pragma unroll
            for (int e = 0; e < 4; ++e) {
                int lin = idx * 4 + e;
                int r = lin / 255;
                int d = lin - r * 255;
                unsigned short us = f2h(vv[e]);
                if (r < 8)       rqT[d][r] = us;
                else if (r < 16) rkT[d][r - 8] = us;
                else if (r < 24) rvA[d][r - 16] = us;
                else             rvB[d][r - 24] = us;
            }
        }
    }
    __syncthreads();

    float cA = scaleS[g], cB = F_QR * scaleS[8 + g], cC = F_KR * scaleS[16 + g];
    float shsum = shiftS[g] + shiftS[8 + g] + shiftS[16 + g];

    int w = t >> 6, l = t & 63;
    int lr = l & 15, lh = l >> 4;
    int i0 = w * 32 + lr;

    half2v q2[2][4];
    {
        uint4 qv0 = *(const uint4*)&qT[i0][0];
        uint4 qv1 = *(const uint4*)&qT[i0 + 16][0];
        q2[0][0] = *(half2v*)&qv0.x; q2[0][1] = *(half2v*)&qv0.y;
        q2[0][2] = *(half2v*)&qv0.z; q2[0][3] = *(half2v*)&qv0.w;
        q2[1][0] = *(half2v*)&qv1.x; q2[1][1] = *(half2v*)&qv1.y;
        q2[1][2] = *(half2v*)&qv1.z; q2[1][3] = *(half2v*)&qv1.w;
    }

    float p0[32], p1[32];
    float rm0 = -1e30f, rm1 = -1e30f;
#pragma unroll
    for (int ks = 0; ks < 4; ++ks) {
#pragma unroll
        for (int e = 0; e < 8; ++e) {
            int j = ks * 32 + lh * 8 + e;
            uint4 kv = *(const uint4*)&kF[j][0];
            half2v* k2p = (half2v*)&kv;
#pragma unroll
            for (int it2 = 0; it2 < 2; ++it2) {
                int i = i0 + it2 * 16;
                uint4 rq = *(const uint4*)&rqT[i - j + 127][0];
                uint4 rk = *(const uint4*)&rkT[j - i + 127][0];
                half2v* rq2p = (half2v*)&rq;
                half2v* rk2p = (half2v*)&rk;
#ifdef HAVE_FDOT2
                float qk = __builtin_amdgcn_fdot2(q2[it2][0], k2p[0],
                           __builtin_amdgcn_fdot2(q2[it2][1], k2p[1],
                           __builtin_amdgcn_fdot2(q2[it2][2], k2p[2],
                           __builtin_amdgcn_fdot2(q2[it2][3], k2p[3], 0.f, false), false), false), false);
                float qr = __builtin_amdgcn_fdot2(q2[it2][0], rq2p[0],
                           __builtin_amdgcn_fdot2(q2[it2][1], rq2p[1],
                           __builtin_amdgcn_fdot2(q2[it2][2], rq2p[2],
                           __builtin_amdgcn_fdot2(q2[it2][3], rq2p[3], 0.f, false), false), false), false);
                float kr = __builtin_amdgcn_fdot2(k2p[0], rk2p[0],
                           __builtin_amdgcn_fdot2(k2p[1], rk2p[1],
                           __builtin_amdgcn_fdot2(k2p[2], rk2p[2],
                           __builtin_amdgcn_fdot2(k2p[3], rk2p[3], 0.f, false), false), false), false);
#else
                __half2* qh = (__half2*)&q2[it2][0];
                __half2* kk2 = (__half2*)&kv;
                __half2* rq2 = (__half2*)&rq;
                __half2* rk2 = (__half2*)&rk;
                __half2 hqk = __hfma2(qh[0], kk2[0], __hfma2(qh[1], kk2[1],
                              __hfma2(qh[2], kk2[2], __hmul2(qh[3], kk2[3]))));
                __half2 hqr = __hfma2(qh[0], rq2[0], __hfma2(qh[1], rq2[1],
                              __hfma2(qh[2], rq2[2], __hmul2(qh[3], rq2[3]))));
                __half2 hkr = __hfma2(kk2[0], rk2[0], __hfma2(kk2[1], rk2[1],
                              __hfma2(kk2[2], rk2[2], __hmul2(kk2[3], rk2[3]))));
                float qk = __low2float(hqk) + __high2float(hqk);
                float qr = __low2float(hqr) + __high2float(hqr);
                float kr = __low2float(hkr) + __high2float(hkr);
#endif
                float s = fmaf(qk, cA, fmaf(qr, cB, fmaf(kr, cC, shsum)));
                if (it2 == 0) { p0[ks * 8 + e] = s; rm0 = fmaxf(rm0, s); }
                else          { p1[ks * 8 + e] = s; rm1 = fmaxf(rm1, s); }
            }
        }
    }
    rm0 = fmaxf(rm0, __shfl_xor(rm0, 16)); rm0 = fmaxf(rm0, __shfl_xor(rm0, 32));
    rm1 = fmaxf(rm1, __shfl_xor(rm1, 16)); rm1 = fmaxf(rm1, __shfl_xor(rm1, 32));
    float rs0 = 0.f, rs1 = 0.f;
#pragma unroll
    for (int kk = 0; kk < 32; ++kk) {
        p0[kk] = __expf(p0[kk] - rm0); rs0 += p0[kk];
        p1[kk] = __expf(p1[kk] - rm1); rs1 += p1[kk];
    }
    rs0 += __shfl_xor(rs0, 16); rs0 += __shfl_xor(rs0, 32);
    rs1 += __shfl_xor(rs1, 16); rs1 += __shfl_xor(rs1, 32);
    float rn0 = 1.f / rs0, rn1 = 1.f / rs1;

    // ---- sve: raw-exp f16 accumulation ----
    __half2 accA2[8], accB2[8];
#pragma unroll
    for (int m = 0; m < 8; ++m) {
        accA2[m] = __floats2half2_rn(0.f, 0.f);
        accB2[m] = __floats2half2_rn(0.f, 0.f);
    }
#pragma unroll
    for (int ks = 0; ks < 4; ++ks) {
#pragma unroll
        for (int e = 0; e < 8; ++e) {
            int j = ks * 32 + lh * 8 + e;
            {
                int d = i0 - j + 127;
                __half2 p2 = __float2half2_rn(p0[ks * 8 + e]);
                uint4 ra = *(const uint4*)&rvA[d][0];
                uint4 rb = *(const uint4*)&rvB[d][0];
                __half2* ra2 = (__half2*)&ra;
                __half2* rb2 = (__half2*)&rb;
                accA2[0] = __hfma2(p2, ra2[0], accA2[0]);
                accA2[1] = __hfma2(p2, ra2[1], accA2[1]);
                accA2[2] = __hfma2(p2, ra2[2], accA2[2]);
                accA2[3] = __hfma2(p2, ra2[3], accA2[3]);
                accA2[4] = __hfma2(p2, rb2[0], accA2[4]);
                accA2[5] = __hfma2(p2, rb2[1], accA2[5]);
                accA2[6] = __hfma2(p2, rb2[2], accA2[6]);
                accA2[7] = __hfma2(p2, rb2[3], accA2[7]);
            }
            {
                int d = i0 + 16 - j + 127;
                __half2 p2 = __float2half2_rn(p1[ks * 8 + e]);
                uint4 ra = *(const uint4*)&rvA[d][0];
                uint4 rb = *(const uint4*)&rvB[d][0];
                __half2* ra2 = (__half2*)&ra;
                __half2* rb2 = (__half2*)&rb;
                accB2[0] = __hfma2(p2, ra2[0], accB2[0]);
                accB2[1] = __hfma2(p2, ra2[1], accB2[1]);
                accB2[2] = __hfma2(p2, ra2[2], accB2[2]);
                accB2[3] = __hfma2(p2, ra2[3], accB2[3]);
                accB2[4] = __hfma2(p2, rb2[0], accB2[4]);
                accB2[5] = __hfma2(p2, rb2[1], accB2[5]);
                accB2[6] = __hfma2(p2, rb2[2], accB2[6]);
                accB2[7] = __hfma2(p2, rb2[3], accB2[7]);
            }
        }
    }
#pragma unroll
    for (int m = 0; m < 8; ++m) {
        unsigned ua = *(unsigned*)&accA2[m];
        unsigned t1 = __shfl_xor(ua, 16);
        accA2[m] = __hadd2(accA2[m], *(__half2*)&t1);
        ua = *(unsigned*)&accA2[m];
        t1 = __shfl_xor(ua, 32);
        accA2[m] = __hadd2(accA2[m], *(__half2*)&t1);
        unsigned ub = *(unsigned*)&accB2[m];
        unsigned t2 = __shfl_xor(ub, 16);
        accB2[m] = __hadd2(accB2[m], *(__half2*)&t2);
        ub = *(unsigned*)&accB2[m];
        t2 = __shfl_xor(ub, 32);
        accB2[m] = __hadd2(accB2[m], *(__half2*)&t2);
    }
    {
        float sce0 = F_SVE * rn0, sce1 = F_SVE * rn1;
        float s_c[4], ss_c[4];
#pragma unroll
        for (int cc = 0; cc < 4; ++cc) {
            int c = lh * 4 + cc;
            __half2 ha = accA2[c >> 1];
            __half2 hb = accB2[c >> 1];
            float v0 = ((c & 1) ? __high2float(ha) : __low2float(ha)) * sce0;
            float v1 = ((c & 1) ? __high2float(hb) : __low2float(hb)) * sce1;
            size_t base = ((size_t)b * CQKV + g * 32 + 2 * c + 1) * HLEN;
            so[base + i0]      = f2h(v0);
            so[base + i0 + 16] = f2h(v1);
            s_c[cc]  = v0 + v1;
            ss_c[cc] = v0 * v0 + v1 * v1;
        }
#pragma unroll
        for (int off = 1; off < 16; off <<= 1) {
#pragma unroll
            for (int cc = 0; cc < 4; ++cc) {
                s_c[cc]  += __shfl_xor(s_c[cc], off);
                ss_c[cc] += __shfl_xor(ss_c[cc], off);
            }
        }
        if (lr == 0) {
#pragma unroll
            for (int cc = 0; cc < 4; ++cc) {
                int c = lh * 4 + cc;
                atomicAdd(&accL[2 * c + 1][0], s_c[cc]);
                atomicAdd(&accL[2 * c + 1][1], ss_c[cc]);
            }
        }
    }

    // ---- pack P*rn into A-fragment registers ----
    unsigned ph[32];
#pragma unroll
    for (int ks = 0; ks < 4; ++ks) {
#pragma unroll
        for (int e2 = 0; e2 < 4; ++e2) {
            __half2 h0 = __floats2half2_rn(p0[ks * 8 + 2 * e2] * rn0,
                                           p0[ks * 8 + 2 * e2 + 1] * rn0);
            __half2 h1 = __floats2half2_rn(p1[ks * 8 + 2 * e2] * rn1,
                                           p1[ks * 8 + 2 * e2 + 1] * rn1);
            ph[ks * 4 + e2]      = *(unsigned*)&h0;
            ph[16 + ks * 4 + e2] = *(unsigned*)&h1;
        }
    }

    // ---- sv via MFMA (A direct from registers) + fused stats ----
    {
        float s0 = 0.f, ss0 = 0.f;
#pragma unroll
        for (int it2 = 0; it2 < 2; ++it2) {
            int itile = w * 2 + it2;
            float4v acc = {0.f, 0.f, 0.f, 0.f};
#pragma unroll
            for (int ks = 0; ks < 4; ++ks) {
                half8v af = *(half8v*)&ph[it2 * 16 + ks * 4];
                half8v bf = *(const half8v*)&vB[lr][ks * 32 + lh * 8];
                acc = __builtin_amdgcn_mfma_f32_16x16x32_f16(af, bf, acc, 0, 0, 0);
            }
            int oc = g * 32 + 2 * lr;
            float ox = acc[0] * F_SV, oy = acc[1] * F_SV;
            float oz = acc[2] * F_SV, ow = acc[3] * F_SV;
            __half2 o01 = __floats2half2_rn(ox, oy);
            __half2 o23 = __floats2half2_rn(oz, ow);
            uint2 pk; pk.x = *(unsigned*)&o01; pk.y = *(unsigned*)&o23;
            *(uint2*)(so + ((size_t)b * CQKV + oc) * HLEN + itile * 16 + lh * 4) = pk;
            s0  += ox + oy + oz + ow;
            ss0 += ox * ox + oy * oy + oz * oz + ow * ow;
        }
        s0  += __shfl_xor(s0, 16);  s0  += __shfl_xor(s0, 32);
        ss0 += __shfl_xor(ss0, 16); ss0 += __shfl_xor(ss0, 32);
        if (lh == 0) {
            atomicAdd(&accL[2 * lr][0], s0);
            atomicAdd(&accL[2 * lr][1], ss0);
        }
    }
    __syncthreads();
    if (t < 32) {
        int o = g * 32 + t;
        atomicAdd(&accF[(size_t)o * 2 + 0], (double)accL[t][0]);
        atomicAdd(&accF[(size_t)o * 2 + 1], (double)accL[t][1]);
    }
}

// ---------------------------------------------------------------------------
// Final affine + pair-sum + transpose (f16 in, f32 out)
// ---------------------------------------------------------------------------
__global__ __launch_bounds__(256) void k_out(const unsigned short* __restrict__ so,
                                             const float* __restrict__ scale,
                                             const float* __restrict__ shift,
                                             float* __restrict__ out) {
    int b = blockIdx.x, n = b >> 6, wi = b & 63;
    int t = threadIdx.x;
    int h4  = (t & 31) << 2;
    int oc0 = (t >> 5) << 4;
    for (int k = 0; k < 16; ++k) {
        int oc = oc0 + k;
        uint2 u0 = *(const uint2*)(so + ((size_t)b * CQKV + 2 * oc) * HLEN + h4);
        uint2 u1 = *(const uint2*)(so + ((size_t)b * CQKV + 2 * oc + 1) * HLEN + h4);
        __half2 a0 = *(__half2*)&u0.x, a1 = *(__half2*)&u0.y;
        __half2 b0 = *(__half2*)&u1.x, b1 = *(__half2*)&u1.y;
        float s0 = scale[2 * oc], f0 = shift[2 * oc];
        float s1 = scale[2 * oc + 1], f1 = shift[2 * oc + 1];
        float4 o4;
        o4.x = fmaf(__low2float(a0),  s0, f0) + fmaf(__low2float(b0),  s1, f1);
        o4.y = fmaf(__high2float(a0), s0, f0) + fmaf(__high2float(b0), s1, f1);
        o4.z = fmaf(__low2float(a1),  s0, f0) + fmaf(__low2float(b1),  s1, f1);
        o4.w = fmaf(__high2float(a1), s0, f0) + fmaf(__high2float(b1), s1, f1);
        *(float4*)(out + (((size_t)n * 128 + oc) * 64 + wi) * HLEN + h4) = o4;
    }
}

extern "C" void kernel_launch(void* const* d_in, const int* in_sizes, int n_in,
                              void* d_out, int out_size, void* d_ws, size_t ws_size,
                              hipStream_t stream) {
    const float* x   = (const float*)d_in[0];
    const float* w   = (const float*)d_in[1];
    const float* g1  = (const float*)d_in[2];
    const float* b1  = (const float*)d_in[3];
    const float* g2  = (const float*)d_in[4];
    const float* b2  = (const float*)d_in[5];
    const float* gs  = (const float*)d_in[6];
    const float* bs  = (const float*)d_in[7];
    const float* go  = (const float*)d_in[8];
    const float* bo  = (const float*)d_in[9];
    const float* rel = (const float*)d_in[10];
    float* out = (float*)d_out;

    unsigned short* qkv = (unsigned short*)d_ws;        // 16,777,216 f16
    unsigned short* so  = qkv + (size_t)16777216;       // 16,777,216 f16
    double* accA   = (double*)(so + (size_t)16777216);  // 512 d (64MB offset, aligned)
    double* accS   = accA + 512;                        // 48 d
    double* accF   = accS + 48;                         // 512 d
    float*  scaleA = (float*)(accF + 512);
    float*  shiftA = scaleA + 256;
    float*  scaleS = shiftA + 256;                      // 24
    float*  shiftS = scaleS + 24;
    float*  scaleF = shiftS + 24;                       // 256
    float*  shiftF = scaleF + 256;
    float*  Rq     = shiftF + 256;                      // 1024
    float*  Rk     = Rq + 1024;                         // 1024
    float*  TqT    = Rk + 1024;                         // 8192
    float*  TkT    = TqT + 8192;                        // 8192

    hipMemsetAsync(accA, 0, (512 + 48 + 512) * sizeof(double), stream);

    k_qkv<<<1024, 256, 0, stream>>>(x, w, qkv, accA);
    k_tables<<<128, 128, 0, stream>>>(rel, Rq, Rk, TqT, TkT);
    k_finA<<<1, 256, 0, stream>>>(accA, g1, g2, b2, scaleA, shiftA);
    k_gram<<<4096, 256, 0, stream>>>(qkv, scaleA, shiftA, Rq, Rk, TqT, TkT, accS);
    k_sfin<<<1, 32, 0, stream>>>(accS, gs, bs, scaleS, shiftS);
    k_attn<<<4096, 256, 0, stream>>>(qkv, scaleA, shiftA, rel, scaleS, shiftS, so, accF);
    k_finF<<<1, 256, 0, stream>>>(accF, go, bo, scaleF, shiftF);
    k_out<<<512, 256, 0, stream>>>(so, scaleF, shiftF, out);
}

// Round 14
// 309.844 us; speedup vs baseline: 1.1960x; 1.1960x over previous
//
#include <hip/hip_runtime.h>
#include <hip/hip_fp16.h>
#include <math.h>

#define B_TOT 512
#define CQKV  256
#define CIN   128
#define HLEN  128

static constexpr float F_QR = 0.3f, F_KR = 0.3f, F_SV = 0.5f, F_SVE = 0.3f;
static constexpr float EPS = 1e-5f;

typedef __attribute__((ext_vector_type(8))) short short8v;
typedef __attribute__((ext_vector_type(8))) _Float16 half8v;
typedef __attribute__((ext_vector_type(2))) _Float16 half2v;
typedef __attribute__((ext_vector_type(4))) float float4v;

#if __has_builtin(__builtin_amdgcn_fdot2)
#define HAVE_FDOT2 1
#endif

__device__ __forceinline__ unsigned short f2bf(float f) {
    unsigned u = __float_as_uint(f);
    unsigned r = u + 0x7fffu + ((u >> 16) & 1u);
    return (unsigned short)(r >> 16);
}
__device__ __forceinline__ unsigned short f2h(float f) {
    return __half_as_ushort(__float2half(f));
}

// ---------------------------------------------------------------------------
// Kernel 1 (MFMA): qkv GEMM + fused per-channel raw stats.
// qkv stored f16 (zero extra score error: k_attn rounds to f16 anyway).
// ---------------------------------------------------------------------------
__global__ __launch_bounds__(256, 3) void k_qkv(const float* __restrict__ x,
                                                const float* __restrict__ w,
                                                unsigned short* __restrict__ qkv,
                                                double* __restrict__ accA) {
    __shared__ unsigned short As[64][136];
    __shared__ unsigned short Xs[256][64];
    __shared__ float wsum[64][2];
    int bid = blockIdx.x;
    int n   = bid >> 7;
    int sub = bid & 127;
    int mt  = sub >> 2;
    int ot  = sub & 3;
    int m0  = mt << 8;
    int o0  = ot << 6;
    int t   = threadIdx.x;

    if (t < 64) { wsum[t][0] = 0.f; wsum[t][1] = 0.f; }

#pragma unroll
    for (int it = 0; it < 8; ++it) {
        int idx = it * 256 + t;
        int o = idx >> 5, c4 = (idx & 31) << 2;
        float4 wv = *(const float4*)(w + (size_t)(o0 + o) * CIN + c4);
        As[o][c4 + 0] = f2bf(wv.x);
        As[o][c4 + 1] = f2bf(wv.y);
        As[o][c4 + 2] = f2bf(wv.z);
        As[o][c4 + 3] = f2bf(wv.w);
    }

    const float* xn = x + (size_t)n * CIN * 8192 + m0;

    int wv_ = t >> 6, l = t & 63;
    int lr = l & 15, lh = l >> 4;
    int mw = wv_ << 6;

    float4v acc[4][4];
#pragma unroll
    for (int a = 0; a < 4; ++a)
#pragma unroll
        for (int b2 = 0; b2 < 4; ++b2) acc[a][b2] = (float4v){0.f, 0.f, 0.f, 0.f};

    for (int s = 0; s < 2; ++s) {
        int c0 = s << 6;
        __syncthreads();
#pragma unroll
        for (int it = 0; it < 16; ++it) {
            int c  = (it << 2) + (t >> 6);
            int m4 = (t & 63) << 2;
            float4 xv = *(const float4*)(xn + (size_t)(c0 + c) * 8192 + m4);
            float vals[4] = {xv.x, xv.y, xv.z, xv.w};
#pragma unroll
            for (int j = 0; j < 4; ++j) {
                int m = m4 + j;
                int cs = (((c >> 3) ^ ((m >> 2) & 7)) << 3) | (c & 7);
                Xs[m][cs] = f2bf(vals[j]);
            }
        }
        __syncthreads();
#pragma unroll
        for (int ks = 0; ks < 2; ++ks) {
            short8v af[4], bf[4];
#pragma unroll
            for (int a = 0; a < 4; ++a)
                af[a] = *(const short8v*)&As[a * 16 + lr][c0 + ks * 32 + lh * 8];
#pragma unroll
            for (int b2 = 0; b2 < 4; ++b2) {
                int m  = mw + b2 * 16 + lr;
                int cb = (ks * 4 + lh) ^ ((m >> 2) & 7);
                bf[b2] = *(const short8v*)&Xs[m][cb << 3];
            }
#pragma unroll
            for (int a = 0; a < 4; ++a)
#pragma unroll
                for (int b2 = 0; b2 < 4; ++b2)
                    acc[a][b2] = __builtin_amdgcn_mfma_f32_16x16x32_bf16(
                        af[a], bf[b2], acc[a][b2], 0, 0, 0);
        }
    }

#pragma unroll
    for (int a = 0; a < 4; ++a) {
#pragma unroll
        for (int b2 = 0; b2 < 4; ++b2) {
            int m  = m0 + mw + b2 * 16 + lr;
            int bb = n * 64 + (m >> 7);
            int h  = m & 127;
#pragma unroll
            for (int r = 0; r < 4; ++r) {
                int o = o0 + a * 16 + lh * 4 + r;
                qkv[((size_t)bb * CQKV + o) * HLEN + h] = f2h(acc[a][b2][r]);
            }
        }
    }

#pragma unroll
    for (int a = 0; a < 4; ++a) {
#pragma unroll
        for (int r = 0; r < 4; ++r) {
            float s = 0.f, ss = 0.f;
#pragma unroll
            for (int b2 = 0; b2 < 4; ++b2) {
                float v = acc[a][b2][r];
                s += v; ss += v * v;
            }
#pragma unroll
            for (int off = 1; off < 16; off <<= 1) {
                s  += __shfl_xor(s, off);
                ss += __shfl_xor(ss, off);
            }
            if (lr == 0) {
                int ol = a * 16 + lh * 4 + r;
                atomicAdd(&wsum[ol][0], s);
                atomicAdd(&wsum[ol][1], ss);
            }
        }
    }
    __syncthreads();
    if (t < 64) {
        atomicAdd(&accA[(size_t)(o0 + t) * 2 + 0], (double)wsum[t][0]);
        atomicAdd(&accA[(size_t)(o0 + t) * 2 + 1], (double)wsum[t][1]);
    }
}

__global__ void k_finA(const double* __restrict__ accA,
                       const float* __restrict__ g1, const float* __restrict__ g2,
                       const float* __restrict__ b2,
                       float* __restrict__ scaleA, float* __restrict__ shiftA) {
    int o = threadIdx.x;
    double cnt  = 65536.0;
    double mean = accA[o * 2] / cnt;
    double var  = accA[o * 2 + 1] / cnt - mean * mean;
    float r1 = rsqrtf((float)var + EPS);
    float v2 = g1[o] * g1[o] * (float)var * r1 * r1;
    float sc = g1[o] * g2[o] * r1 * rsqrtf(v2 + EPS);
    scaleA[o] = sc;
    shiftA[o] = b2[o] - (float)mean * sc;
}

__global__ void k_finF(const double* __restrict__ accF,
                       const float* __restrict__ go, const float* __restrict__ bo,
                       float* __restrict__ scaleF, float* __restrict__ shiftF) {
    int o = threadIdx.x;
    double cnt  = 65536.0;
    double mean = accF[o * 2] / cnt;
    double var  = accF[o * 2 + 1] / cnt - mean * mean;
    float sc = go[o] * rsqrtf((float)var + EPS);
    scaleF[o] = sc;
    shiftF[o] = bo[o] - (float)mean * sc;
}

// ---------------------------------------------------------------------------
// Tables for analytic score stats (f32, for k_gram).
// ---------------------------------------------------------------------------
__global__ __launch_bounds__(128) void k_tables(const float* __restrict__ rel,
                                                float* __restrict__ Rq, float* __restrict__ Rk,
                                                float* __restrict__ TqT, float* __restrict__ TkT) {
    int bid = blockIdx.x;      // 0..127
    int i = threadIdx.x;       // 0..127
    int p = bid & 63;
    int c = p >> 3, c2 = p & 7;
    const float* ra = (bid < 64) ? (rel + c * 255)  : (rel + (8 + c) * 255);
    const float* rb = (bid < 64) ? (rel + c2 * 255) : (rel + (8 + c2) * 255);
    float tacc = 0.f;
    for (int kk = 0; kk < 128; ++kk) tacc = fmaf(ra[i + kk], rb[i + kk], tacc);
    if (bid < 64) TqT[i * 64 + p] = tacc; else TkT[i * 64 + p] = tacc;
    if (c2 == 0) {
        float racc = 0.f;
        for (int kk = 0; kk < 128; ++kk) racc += ra[i + kk];
        if (bid < 64) Rq[c * 128 + i] = racc; else Rk[c * 128 + i] = racc;
    }
}

// ---------------------------------------------------------------------------
// Analytic score stats per (b,g) — 256 threads; qkv is f16.
// ---------------------------------------------------------------------------
__global__ __launch_bounds__(256) void k_gram(const unsigned short* __restrict__ qkv,
                                              const float* __restrict__ scaleA,
                                              const float* __restrict__ shiftA,
                                              const float* __restrict__ Rq,
                                              const float* __restrict__ Rk,
                                              const float* __restrict__ TqT,
                                              const float* __restrict__ TkT,
                                              double* __restrict__ accS) {
    __shared__ float qs[8][132], ks[8][132];
    __shared__ float redA[4][64][4];
    __shared__ float redB[2][18];
    __shared__ float redC[3];
    int blk = blockIdx.x, b = blk >> 3, g = blk & 7;
    int t = threadIdx.x;
    for (int idx = t; idx < 2048; idx += 256) {
        int cc = idx >> 7, h = idx & 127, o = g * 32 + cc;
        float raw = __half2float(__ushort_as_half(qkv[((size_t)b * CQKV + o) * HLEN + h]));
        float v = raw * scaleA[o] + shiftA[o];
        if (cc < 8) qs[cc][h] = v; else ks[cc - 8][h] = v;
    }
    __syncthreads();
    int lane = t & 63, wv = t >> 6;
    int c = lane >> 3, c2 = lane & 7;
    float gq = 0, gk = 0, tq = 0, tk = 0;
#pragma unroll 4
    for (int ii = 0; ii < 32; ++ii) {
        int i = wv * 32 + ii;
        float a = qs[c][i] * qs[c2][i];
        float e = ks[c][i] * ks[c2][i];
        gq += a; gk += e;
        tq = fmaf(a, TqT[i * 64 + lane], tq);
        tk = fmaf(e, TkT[i * 64 + lane], tk);
    }
    redA[wv][lane][0] = gq; redA[wv][lane][1] = gk;
    redA[wv][lane][2] = tq; redA[wv][lane][3] = tk;

    if (t < 128) {
        int h = t;
        float sqr = 0, skr = 0;
        float sq8l[8], sk8l[8];
#pragma unroll
        for (int c3 = 0; c3 < 8; ++c3) {
            float q0 = qs[c3][h], k0 = ks[c3][h];
            sq8l[c3] = q0; sk8l[c3] = k0;
            sqr = fmaf(q0, Rq[c3 * 128 + h], sqr);
            skr = fmaf(k0, Rk[c3 * 128 + h], skr);
        }
#pragma unroll
        for (int off = 1; off < 64; off <<= 1) {
            sqr += __shfl_xor(sqr, off);
            skr += __shfl_xor(skr, off);
#pragma unroll
            for (int c3 = 0; c3 < 8; ++c3) {
                sq8l[c3] += __shfl_xor(sq8l[c3], off);
                sk8l[c3] += __shfl_xor(sk8l[c3], off);
            }
        }
        if (lane == 0) {
            redB[wv][0] = sqr; redB[wv][1] = skr;
#pragma unroll
            for (int c3 = 0; c3 < 8; ++c3) {
                redB[wv][2 + c3]  = sq8l[c3];
                redB[wv][10 + c3] = sk8l[c3];
            }
        }
    }
    __syncthreads();
    if (t < 64) {
        float Gq = redA[0][t][0] + redA[1][t][0] + redA[2][t][0] + redA[3][t][0];
        float Gk = redA[0][t][1] + redA[1][t][1] + redA[2][t][1] + redA[3][t][1];
        float Tq = redA[0][t][2] + redA[1][t][2] + redA[2][t][2] + redA[3][t][2];
        float Tk = redA[0][t][3] + redA[1][t][3] + redA[2][t][3] + redA[3][t][3];
        float ssqk = Gq * Gk;
#pragma unroll
        for (int off = 1; off < 64; off <<= 1) {
            ssqk += __shfl_xor(ssqk, off);
            Tq   += __shfl_xor(Tq, off);
            Tk   += __shfl_xor(Tk, off);
        }
        if (t == 0) { redC[0] = ssqk; redC[1] = Tq; redC[2] = Tk; }
    }
    __syncthreads();
    if (t == 0) {
        float sqr = redB[0][0] + redB[1][0];
        float skr = redB[0][1] + redB[1][1];
        float sqk = 0;
#pragma unroll
        for (int c3 = 0; c3 < 8; ++c3)
            sqk += (redB[0][2 + c3] + redB[1][2 + c3]) * (redB[0][10 + c3] + redB[1][10 + c3]);
        atomicAdd(&accS[g * 2 + 0], (double)sqk);
        atomicAdd(&accS[g * 2 + 1], (double)redC[0]);
        atomicAdd(&accS[(8 + g) * 2 + 0], (double)(F_QR * sqr));
        atomicAdd(&accS[(8 + g) * 2 + 1], (double)(F_QR * F_QR * redC[1]));
        atomicAdd(&accS[(16 + g) * 2 + 0], (double)(F_KR * skr));
        atomicAdd(&accS[(16 + g) * 2 + 1], (double)(F_KR * F_KR * redC[2]));
    }
}

__global__ void k_sfin(const double* __restrict__ accS,
                       const float* __restrict__ gs, const float* __restrict__ bs,
                       float* __restrict__ scaleS, float* __restrict__ shiftS) {
    int c = threadIdx.x;
    if (c < 24) {
        double cnt  = 512.0 * 128.0 * 128.0;
        double mean = accS[c * 2] / cnt;
        double var  = accS[c * 2 + 1] / cnt - mean * mean;
        float sc = gs[c] * rsqrtf((float)var + EPS);
        scaleS[c] = sc;
        shiftS[c] = bs[c] - (float)mean * sc;
    }
}

// ---------------------------------------------------------------------------
// Attention — fragment-native, f16 qkv/so, (256,4): VGPR cap 128 (zero spill;
// the (256,6) variant forced 40 VGPR and spilled p0/p1 -> 600MB scratch I/O).
// ---------------------------------------------------------------------------
__global__ __launch_bounds__(256, 4) void k_attn(const unsigned short* __restrict__ qkv,
                                                 const float* __restrict__ scaleA,
                                                 const float* __restrict__ shiftA,
                                                 const float* __restrict__ rel,
                                                 const float* __restrict__ scaleS,
                                                 const float* __restrict__ shiftS,
                                                 unsigned short* __restrict__ so,
                                                 double* __restrict__ accF) {
    __shared__ unsigned short qT[128][8];
    __shared__ unsigned short kF[128][8];
    __shared__ unsigned short vB[16][136];
    __shared__ unsigned short rqT[255][8];
    __shared__ unsigned short rkT[255][8];
    __shared__ unsigned short rvA[255][8];
    __shared__ unsigned short rvB[255][8];
    __shared__ float accL[32][2];
    int blk = blockIdx.x, b = blk >> 3, g = blk & 7;
    int t = threadIdx.x;
    if (t < 32) { accL[t][0] = 0.f; accL[t][1] = 0.f; }

    // ---- staging: qkv (f16) via uint2, affine in half2 domain ----
#pragma unroll
    for (int it = 0; it < 4; ++it) {
        int idx = it * 256 + t;
        int cc = idx >> 5;
        int h4 = (idx & 31) << 2;
        int o = g * 32 + cc;
        uint2 v4 = *(const uint2*)(qkv + ((size_t)b * CQKV + o) * HLEN + h4);
        __half2 sc2 = __float2half2_rn(scaleA[o]);
        __half2 sh2 = __float2half2_rn(shiftA[o]);
        __half2 va = __hfma2(*(__half2*)&v4.x, sc2, sh2);
        __half2 vb2 = __hfma2(*(__half2*)&v4.y, sc2, sh2);
        unsigned ua = *(unsigned*)&va, ub = *(unsigned*)&vb2;
        if (cc < 8) {
            qT[h4][cc]     = (unsigned short)(ua & 0xffff);
            qT[h4 + 1][cc] = (unsigned short)(ua >> 16);
            qT[h4 + 2][cc] = (unsigned short)(ub & 0xffff);
            qT[h4 + 3][cc] = (unsigned short)(ub >> 16);
        } else if (cc < 16) {
            kF[h4][cc - 8]     = (unsigned short)(ua & 0xffff);
            kF[h4 + 1][cc - 8] = (unsigned short)(ua >> 16);
            kF[h4 + 2][cc - 8] = (unsigned short)(ub & 0xffff);
            kF[h4 + 3][cc - 8] = (unsigned short)(ub >> 16);
        } else {
            uint2 pk; pk.x = ua; pk.y = ub;
            *(uint2*)&vB[cc - 16][h4] = pk;
        }
    }
    // ---- staging: rel via float4 ----
#pragma unroll
    for (int it = 0; it < 8; ++it) {
        int idx = it * 256 + t;
        if (idx < 2040) {
            float4 v = *(const float4*)(rel + (size_t)idx * 4);
            float vv[4] = {v.x, v.y, v.z, v.w};
#pragma unroll
            for (int e = 0; e < 4; ++e) {
                int lin = idx * 4 + e;
                int r = lin / 255;
                int d = lin - r * 255;
                unsigned short us = f2h(vv[e]);
                if (r < 8)       rqT[d][r] = us;
                else if (r < 16) rkT[d][r - 8] = us;
                else if (r < 24) rvA[d][r - 16] = us;
                else             rvB[d][r - 24] = us;
            }
        }
    }
    __syncthreads();

    float cA = scaleS[g], cB = F_QR * scaleS[8 + g], cC = F_KR * scaleS[16 + g];
    float shsum = shiftS[g] + shiftS[8 + g] + shiftS[16 + g];

    int w = t >> 6, l = t & 63;
    int lr = l & 15, lh = l >> 4;
    int i0 = w * 32 + lr;

    half2v q2[2][4];
    {
        uint4 qv0 = *(const uint4*)&qT[i0][0];
        uint4 qv1 = *(const uint4*)&qT[i0 + 16][0];
        q2[0][0] = *(half2v*)&qv0.x; q2[0][1] = *(half2v*)&qv0.y;
        q2[0][2] = *(half2v*)&qv0.z; q2[0][3] = *(half2v*)&qv0.w;
        q2[1][0] = *(half2v*)&qv1.x; q2[1][1] = *(half2v*)&qv1.y;
        q2[1][2] = *(half2v*)&qv1.z; q2[1][3] = *(half2v*)&qv1.w;
    }

    float p0[32], p1[32];
    float rm0 = -1e30f, rm1 = -1e30f;
#pragma unroll
    for (int ks = 0; ks < 4; ++ks) {
#pragma unroll
        for (int e = 0; e < 8; ++e) {
            int j = ks * 32 + lh * 8 + e;
            uint4 kv = *(const uint4*)&kF[j][0];
            half2v* k2p = (half2v*)&kv;
#pragma unroll
            for (int it2 = 0; it2 < 2; ++it2) {
                int i = i0 + it2 * 16;
                uint4 rq = *(const uint4*)&rqT[i - j + 127][0];
                uint4 rk = *(const uint4*)&rkT[j - i + 127][0];
                half2v* rq2p = (half2v*)&rq;
                half2v* rk2p = (half2v*)&rk;
#ifdef HAVE_FDOT2
                float qk = __builtin_amdgcn_fdot2(q2[it2][0], k2p[0],
                           __builtin_amdgcn_fdot2(q2[it2][1], k2p[1],
                           __builtin_amdgcn_fdot2(q2[it2][2], k2p[2],
                           __builtin_amdgcn_fdot2(q2[it2][3], k2p[3], 0.f, false), false), false), false);
                float qr = __builtin_amdgcn_fdot2(q2[it2][0], rq2p[0],
                           __builtin_amdgcn_fdot2(q2[it2][1], rq2p[1],
                           __builtin_amdgcn_fdot2(q2[it2][2], rq2p[2],
                           __builtin_amdgcn_fdot2(q2[it2][3], rq2p[3], 0.f, false), false), false), false);
                float kr = __builtin_amdgcn_fdot2(k2p[0], rk2p[0],
                           __builtin_amdgcn_fdot2(k2p[1], rk2p[1],
                           __builtin_amdgcn_fdot2(k2p[2], rk2p[2],
                           __builtin_amdgcn_fdot2(k2p[3], rk2p[3], 0.f, false), false), false), false);
#else
                __half2* qh = (__half2*)&q2[it2][0];
                __half2* kk2 = (__half2*)&kv;
                __half2* rq2 = (__half2*)&rq;
                __half2* rk2 = (__half2*)&rk;
                __half2 hqk = __hfma2(qh[0], kk2[0], __hfma2(qh[1], kk2[1],
                              __hfma2(qh[2], kk2[2], __hmul2(qh[3], kk2[3]))));
                __half2 hqr = __hfma2(qh[0], rq2[0], __hfma2(qh[1], rq2[1],
                              __hfma2(qh[2], rq2[2], __hmul2(qh[3], rq2[3]))));
                __half2 hkr = __hfma2(kk2[0], rk2[0], __hfma2(kk2[1], rk2[1],
                              __hfma2(kk2[2], rk2[2], __hmul2(kk2[3], rk2[3]))));
                float qk = __low2float(hqk) + __high2float(hqk);
                float qr = __low2float(hqr) + __high2float(hqr);
                float kr = __low2float(hkr) + __high2float(hkr);
#endif
                float s = fmaf(qk, cA, fmaf(qr, cB, fmaf(kr, cC, shsum)));
                if (it2 == 0) { p0[ks * 8 + e] = s; rm0 = fmaxf(rm0, s); }
                else          { p1[ks * 8 + e] = s; rm1 = fmaxf(rm1, s); }
            }
        }
    }
    rm0 = fmaxf(rm0, __shfl_xor(rm0, 16)); rm0 = fmaxf(rm0, __shfl_xor(rm0, 32));
    rm1 = fmaxf(rm1, __shfl_xor(rm1, 16)); rm1 = fmaxf(rm1, __shfl_xor(rm1, 32));
    float rs0 = 0.f, rs1 = 0.f;
#pragma unroll
    for (int kk = 0; kk < 32; ++kk) {
        p0[kk] = __expf(p0[kk] - rm0); rs0 += p0[kk];
        p1[kk] = __expf(p1[kk] - rm1); rs1 += p1[kk];
    }
    rs0 += __shfl_xor(rs0, 16); rs0 += __shfl_xor(rs0, 32);
    rs1 += __shfl_xor(rs1, 16); rs1 += __shfl_xor(rs1, 32);
    float rn0 = 1.f / rs0, rn1 = 1.f / rs1;

    // ---- sve: raw-exp f16 accumulation ----
    __half2 accA2[8], accB2[8];
#pragma unroll
    for (int m = 0; m < 8; ++m) {
        accA2[m] = __floats2half2_rn(0.f, 0.f);
        accB2[m] = __floats2half2_rn(0.f, 0.f);
    }
#pragma unroll
    for (int ks = 0; ks < 4; ++ks) {
#pragma unroll
        for (int e = 0; e < 8; ++e) {
            int j = ks * 32 + lh * 8 + e;
            {
                int d = i0 - j + 127;
                __half2 p2 = __float2half2_rn(p0[ks * 8 + e]);
                uint4 ra = *(const uint4*)&rvA[d][0];
                uint4 rb = *(const uint4*)&rvB[d][0];
                __half2* ra2 = (__half2*)&ra;
                __half2* rb2 = (__half2*)&rb;
                accA2[0] = __hfma2(p2, ra2[0], accA2[0]);
                accA2[1] = __hfma2(p2, ra2[1], accA2[1]);
                accA2[2] = __hfma2(p2, ra2[2], accA2[2]);
                accA2[3] = __hfma2(p2, ra2[3], accA2[3]);
                accA2[4] = __hfma2(p2, rb2[0], accA2[4]);
                accA2[5] = __hfma2(p2, rb2[1], accA2[5]);
                accA2[6] = __hfma2(p2, rb2[2], accA2[6]);
                accA2[7] = __hfma2(p2, rb2[3], accA2[7]);
            }
            {
                int d = i0 + 16 - j + 127;
                __half2 p2 = __float2half2_rn(p1[ks * 8 + e]);
                uint4 ra = *(const uint4*)&rvA[d][0];
                uint4 rb = *(const uint4*)&rvB[d][0];
                __half2* ra2 = (__half2*)&ra;
                __half2* rb2 = (__half2*)&rb;
                accB2[0] = __hfma2(p2, ra2[0], accB2[0]);
                accB2[1] = __hfma2(p2, ra2[1], accB2[1]);
                accB2[2] = __hfma2(p2, ra2[2], accB2[2]);
                accB2[3] = __hfma2(p2, ra2[3], accB2[3]);
                accB2[4] = __hfma2(p2, rb2[0], accB2[4]);
                accB2[5] = __hfma2(p2, rb2[1], accB2[5]);
                accB2[6] = __hfma2(p2, rb2[2], accB2[6]);
                accB2[7] = __hfma2(p2, rb2[3], accB2[7]);
            }
        }
    }
#pragma unroll
    for (int m = 0; m < 8; ++m) {
        unsigned ua = *(unsigned*)&accA2[m];
        unsigned t1 = __shfl_xor(ua, 16);
        accA2[m] = __hadd2(accA2[m], *(__half2*)&t1);
        ua = *(unsigned*)&accA2[m];
        t1 = __shfl_xor(ua, 32);
        accA2[m] = __hadd2(accA2[m], *(__half2*)&t1);
        unsigned ub = *(unsigned*)&accB2[m];
        unsigned t2 = __shfl_xor(ub, 16);
        accB2[m] = __hadd2(accB2[m], *(__half2*)&t2);
        ub = *(unsigned*)&accB2[m];
        t2 = __shfl_xor(ub, 32);
        accB2[m] = __hadd2(accB2[m], *(__half2*)&t2);
    }
    {
        float sce0 = F_SVE * rn0, sce1 = F_SVE * rn1;
        float s_c[4], ss_c[4];
#pragma unroll
        for (int cc = 0; cc < 4; ++cc) {
            int c = lh * 4 + cc;
            __half2 ha = accA2[c >> 1];
            __half2 hb = accB2[c >> 1];
            float v0 = ((c & 1) ? __high2float(ha) : __low2float(ha)) * sce0;
            float v1 = ((c & 1) ? __high2float(hb) : __low2float(hb)) * sce1;
            size_t base = ((size_t)b * CQKV + g * 32 + 2 * c + 1) * HLEN;
            so[base + i0]      = f2h(v0);
            so[base + i0 + 16] = f2h(v1);
            s_c[cc]  = v0 + v1;
            ss_c[cc] = v0 * v0 + v1 * v1;
        }
#pragma unroll
        for (int off = 1; off < 16; off <<= 1) {
#pragma unroll
            for (int cc = 0; cc < 4; ++cc) {
                s_c[cc]  += __shfl_xor(s_c[cc], off);
                ss_c[cc] += __shfl_xor(ss_c[cc], off);
            }
        }
        if (lr == 0) {
#pragma unroll
            for (int cc = 0; cc < 4; ++cc) {
                int c = lh * 4 + cc;
                atomicAdd(&accL[2 * c + 1][0], s_c[cc]);
                atomicAdd(&accL[2 * c + 1][1], ss_c[cc]);
            }
        }
    }

    // ---- pack P*rn into A-fragment registers ----
    unsigned ph[32];
#pragma unroll
    for (int ks = 0; ks < 4; ++ks) {
#pragma unroll
        for (int e2 = 0; e2 < 4; ++e2) {
            __half2 h0 = __floats2half2_rn(p0[ks * 8 + 2 * e2] * rn0,
                                           p0[ks * 8 + 2 * e2 + 1] * rn0);
            __half2 h1 = __floats2half2_rn(p1[ks * 8 + 2 * e2] * rn1,
                                           p1[ks * 8 + 2 * e2 + 1] * rn1);
            ph[ks * 4 + e2]      = *(unsigned*)&h0;
            ph[16 + ks * 4 + e2] = *(unsigned*)&h1;
        }
    }

    // ---- sv via MFMA (A direct from registers) + fused stats ----
    {
        float s0 = 0.f, ss0 = 0.f;
#pragma unroll
        for (int it2 = 0; it2 < 2; ++it2) {
            int itile = w * 2 + it2;
            float4v acc = {0.f, 0.f, 0.f, 0.f};
#pragma unroll
            for (int ks = 0; ks < 4; ++ks) {
                half8v af = *(half8v*)&ph[it2 * 16 + ks * 4];
                half8v bf = *(const half8v*)&vB[lr][ks * 32 + lh * 8];
                acc = __builtin_amdgcn_mfma_f32_16x16x32_f16(af, bf, acc, 0, 0, 0);
            }
            int oc = g * 32 + 2 * lr;
            float ox = acc[0] * F_SV, oy = acc[1] * F_SV;
            float oz = acc[2] * F_SV, ow = acc[3] * F_SV;
            __half2 o01 = __floats2half2_rn(ox, oy);
            __half2 o23 = __floats2half2_rn(oz, ow);
            uint2 pk; pk.x = *(unsigned*)&o01; pk.y = *(unsigned*)&o23;
            *(uint2*)(so + ((size_t)b * CQKV + oc) * HLEN + itile * 16 + lh * 4) = pk;
            s0  += ox + oy + oz + ow;
            ss0 += ox * ox + oy * oy + oz * oz + ow * ow;
        }
        s0  += __shfl_xor(s0, 16);  s0  += __shfl_xor(s0, 32);
        ss0 += __shfl_xor(ss0, 16); ss0 += __shfl_xor(ss0, 32);
        if (lh == 0) {
            atomicAdd(&accL[2 * lr][0], s0);
            atomicAdd(&accL[2 * lr][1], ss0);
        }
    }
    __syncthreads();
    if (t < 32) {
        int o = g * 32 + t;
        atomicAdd(&accF[(size_t)o * 2 + 0], (double)accL[t][0]);
        atomicAdd(&accF[(size_t)o * 2 + 1], (double)accL[t][1]);
    }
}

// ---------------------------------------------------------------------------
// Final affine + pair-sum + transpose (f16 in, f32 out)
// ---------------------------------------------------------------------------
__global__ __launch_bounds__(256) void k_out(const unsigned short* __restrict__ so,
                                             const float* __restrict__ scale,
                                             const float* __restrict__ shift,
                                             float* __restrict__ out) {
    int b = blockIdx.x, n = b >> 6, wi = b & 63;
    int t = threadIdx.x;
    int h4  = (t & 31) << 2;
    int oc0 = (t >> 5) << 4;
    for (int k = 0; k < 16; ++k) {
        int oc = oc0 + k;
        uint2 u0 = *(const uint2*)(so + ((size_t)b * CQKV + 2 * oc) * HLEN + h4);
        uint2 u1 = *(const uint2*)(so + ((size_t)b * CQKV + 2 * oc + 1) * HLEN + h4);
        __half2 a0 = *(__half2*)&u0.x, a1 = *(__half2*)&u0.y;
        __half2 b0 = *(__half2*)&u1.x, b1 = *(__half2*)&u1.y;
        float s0 = scale[2 * oc], f0 = shift[2 * oc];
        float s1 = scale[2 * oc + 1], f1 = shift[2 * oc + 1];
        float4 o4;
        o4.x = fmaf(__low2float(a0),  s0, f0) + fmaf(__low2float(b0),  s1, f1);
        o4.y = fmaf(__high2float(a0), s0, f0) + fmaf(__high2float(b0), s1, f1);
        o4.z = fmaf(__low2float(a1),  s0, f0) + fmaf(__low2float(b1),  s1, f1);
        o4.w = fmaf(__high2float(a1), s0, f0) + fmaf(__high2float(b1), s1, f1);
        *(float4*)(out + (((size_t)n * 128 + oc) * 64 + wi) * HLEN + h4) = o4;
    }
}

extern "C" void kernel_launch(void* const* d_in, const int* in_sizes, int n_in,
                              void* d_out, int out_size, void* d_ws, size_t ws_size,
                              hipStream_t stream) {
    const float* x   = (const float*)d_in[0];
    const float* w   = (const float*)d_in[1];
    const float* g1  = (const float*)d_in[2];
    const float* b1  = (const float*)d_in[3];
    const float* g2  = (const float*)d_in[4];
    const float* b2  = (const float*)d_in[5];
    const float* gs  = (const float*)d_in[6];
    const float* bs  = (const float*)d_in[7];
    const float* go  = (const float*)d_in[8];
    const float* bo  = (const float*)d_in[9];
    const float* rel = (const float*)d_in[10];
    float* out = (float*)d_out;

    unsigned short* qkv = (unsigned short*)d_ws;        // 16,777,216 f16
    unsigned short* so  = qkv + (size_t)16777216;       // 16,777,216 f16
    double* accA   = (double*)(so + (size_t)16777216);  // 512 d
    double* accS   = accA + 512;                        // 48 d
    double* accF   = accS + 48;                         // 512 d
    float*  scaleA = (float*)(accF + 512);
    float*  shiftA = scaleA + 256;
    float*  scaleS = shiftA + 256;                      // 24
    float*  shiftS = scaleS + 24;
    float*  scaleF = shiftS + 24;                       // 256
    float*  shiftF = scaleF + 256;
    float*  Rq     = shiftF + 256;                      // 1024
    float*  Rk     = Rq + 1024;                         // 1024
    float*  TqT    = Rk + 1024;                         // 8192
    float*  TkT    = TqT + 8192;                        // 8192

    hipMemsetAsync(accA, 0, (512 + 48 + 512) * sizeof(double), stream);

    k_qkv<<<1024, 256, 0, stream>>>(x, w, qkv, accA);
    k_tables<<<128, 128, 0, stream>>>(rel, Rq, Rk, TqT, TkT);
    k_finA<<<1, 256, 0, stream>>>(accA, g1, g2, b2, scaleA, shiftA);
    k_gram<<<4096, 256, 0, stream>>>(qkv, scaleA, shiftA, Rq, Rk, TqT, TkT, accS);
    k_sfin<<<1, 32, 0, stream>>>(accS, gs, bs, scaleS, shiftS);
    k_attn<<<4096, 256, 0, stream>>>(qkv, scaleA, shiftA, rel, scaleS, shiftS, so, accF);
    k_finF<<<1, 256, 0, stream>>>(accF, go, bo, scaleF, shiftF);
    k_out<<<512, 256, 0, stream>>>(so, scaleF, shiftF, out);
}

// Round 15
// 309.703 us; speedup vs baseline: 1.1965x; 1.0005x over previous
//
#include <hip/hip_runtime.h>
#include <hip/hip_fp16.h>
#include <math.h>

#define B_TOT 512
#define CQKV  256
#define CIN   128
#define HLEN  128

static constexpr float F_QR = 0.3f, F_KR = 0.3f, F_SV = 0.5f, F_SVE = 0.3f;
static constexpr float EPS = 1e-5f;

typedef __attribute__((ext_vector_type(8))) short short8v;
typedef __attribute__((ext_vector_type(8))) _Float16 half8v;
typedef __attribute__((ext_vector_type(2))) _Float16 half2v;
typedef __attribute__((ext_vector_type(4))) float float4v;

#if __has_builtin(__builtin_amdgcn_fdot2)
#define HAVE_FDOT2 1
#endif

__device__ __forceinline__ unsigned short f2bf(float f) {
    unsigned u = __float_as_uint(f);
    unsigned r = u + 0x7fffu + ((u >> 16) & 1u);
    return (unsigned short)(r >> 16);
}
__device__ __forceinline__ unsigned short f2h(float f) {
    return __half_as_ushort(__float2half(f));
}

// ---------------------------------------------------------------------------
// Kernel 1 (MFMA): qkv GEMM + fused per-channel raw stats.
// qkv stored f16 (zero extra score error: k_attn rounds to f16 anyway).
// ---------------------------------------------------------------------------
__global__ __launch_bounds__(256, 3) void k_qkv(const float* __restrict__ x,
                                                const float* __restrict__ w,
                                                unsigned short* __restrict__ qkv,
                                                double* __restrict__ accA) {
    __shared__ unsigned short As[64][136];
    __shared__ unsigned short Xs[256][64];
    __shared__ float wsum[64][2];
    int bid = blockIdx.x;
    int n   = bid >> 7;
    int sub = bid & 127;
    int mt  = sub >> 2;
    int ot  = sub & 3;
    int m0  = mt << 8;
    int o0  = ot << 6;
    int t   = threadIdx.x;

    if (t < 64) { wsum[t][0] = 0.f; wsum[t][1] = 0.f; }

#pragma unroll
    for (int it = 0; it < 8; ++it) {
        int idx = it * 256 + t;
        int o = idx >> 5, c4 = (idx & 31) << 2;
        float4 wv = *(const float4*)(w + (size_t)(o0 + o) * CIN + c4);
        As[o][c4 + 0] = f2bf(wv.x);
        As[o][c4 + 1] = f2bf(wv.y);
        As[o][c4 + 2] = f2bf(wv.z);
        As[o][c4 + 3] = f2bf(wv.w);
    }

    const float* xn = x + (size_t)n * CIN * 8192 + m0;

    int wv_ = t >> 6, l = t & 63;
    int lr = l & 15, lh = l >> 4;
    int mw = wv_ << 6;

    float4v acc[4][4];
#pragma unroll
    for (int a = 0; a < 4; ++a)
#pragma unroll
        for (int b2 = 0; b2 < 4; ++b2) acc[a][b2] = (float4v){0.f, 0.f, 0.f, 0.f};

    for (int s = 0; s < 2; ++s) {
        int c0 = s << 6;
        __syncthreads();
#pragma unroll
        for (int it = 0; it < 16; ++it) {
            int c  = (it << 2) + (t >> 6);
            int m4 = (t & 63) << 2;
            float4 xv = *(const float4*)(xn + (size_t)(c0 + c) * 8192 + m4);
            float vals[4] = {xv.x, xv.y, xv.z, xv.w};
#pragma unroll
            for (int j = 0; j < 4; ++j) {
                int m = m4 + j;
                int cs = (((c >> 3) ^ ((m >> 2) & 7)) << 3) | (c & 7);
                Xs[m][cs] = f2bf(vals[j]);
            }
        }
        __syncthreads();
#pragma unroll
        for (int ks = 0; ks < 2; ++ks) {
            short8v af[4], bf[4];
#pragma unroll
            for (int a = 0; a < 4; ++a)
                af[a] = *(const short8v*)&As[a * 16 + lr][c0 + ks * 32 + lh * 8];
#pragma unroll
            for (int b2 = 0; b2 < 4; ++b2) {
                int m  = mw + b2 * 16 + lr;
                int cb = (ks * 4 + lh) ^ ((m >> 2) & 7);
                bf[b2] = *(const short8v*)&Xs[m][cb << 3];
            }
#pragma unroll
            for (int a = 0; a < 4; ++a)
#pragma unroll
                for (int b2 = 0; b2 < 4; ++b2)
                    acc[a][b2] = __builtin_amdgcn_mfma_f32_16x16x32_bf16(
                        af[a], bf[b2], acc[a][b2], 0, 0, 0);
        }
    }

#pragma unroll
    for (int a = 0; a < 4; ++a) {
#pragma unroll
        for (int b2 = 0; b2 < 4; ++b2) {
            int m  = m0 + mw + b2 * 16 + lr;
            int bb = n * 64 + (m >> 7);
            int h  = m & 127;
#pragma unroll
            for (int r = 0; r < 4; ++r) {
                int o = o0 + a * 16 + lh * 4 + r;
                qkv[((size_t)bb * CQKV + o) * HLEN + h] = f2h(acc[a][b2][r]);
            }
        }
    }

#pragma unroll
    for (int a = 0; a < 4; ++a) {
#pragma unroll
        for (int r = 0; r < 4; ++r) {
            float s = 0.f, ss = 0.f;
#pragma unroll
            for (int b2 = 0; b2 < 4; ++b2) {
                float v = acc[a][b2][r];
                s += v; ss += v * v;
            }
#pragma unroll
            for (int off = 1; off < 16; off <<= 1) {
                s  += __shfl_xor(s, off);
                ss += __shfl_xor(ss, off);
            }
            if (lr == 0) {
                int ol = a * 16 + lh * 4 + r;
                atomicAdd(&wsum[ol][0], s);
                atomicAdd(&wsum[ol][1], ss);
            }
        }
    }
    __syncthreads();
    if (t < 64) {
        atomicAdd(&accA[(size_t)(o0 + t) * 2 + 0], (double)wsum[t][0]);
        atomicAdd(&accA[(size_t)(o0 + t) * 2 + 1], (double)wsum[t][1]);
    }
}

__global__ void k_finA(const double* __restrict__ accA,
                       const float* __restrict__ g1, const float* __restrict__ g2,
                       const float* __restrict__ b2,
                       float* __restrict__ scaleA, float* __restrict__ shiftA) {
    int o = threadIdx.x;
    double cnt  = 65536.0;
    double mean = accA[o * 2] / cnt;
    double var  = accA[o * 2 + 1] / cnt - mean * mean;
    float r1 = rsqrtf((float)var + EPS);
    float v2 = g1[o] * g1[o] * (float)var * r1 * r1;
    float sc = g1[o] * g2[o] * r1 * rsqrtf(v2 + EPS);
    scaleA[o] = sc;
    shiftA[o] = b2[o] - (float)mean * sc;
}

__global__ void k_finF(const double* __restrict__ accF,
                       const float* __restrict__ go, const float* __restrict__ bo,
                       float* __restrict__ scaleF, float* __restrict__ shiftF) {
    int o = threadIdx.x;
    double cnt  = 65536.0;
    double mean = accF[o * 2] / cnt;
    double var  = accF[o * 2 + 1] / cnt - mean * mean;
    float sc = go[o] * rsqrtf((float)var + EPS);
    scaleF[o] = sc;
    shiftF[o] = bo[o] - (float)mean * sc;
}

// ---------------------------------------------------------------------------
// Tables for analytic score stats (f32, for k_gram).
// ---------------------------------------------------------------------------
__global__ __launch_bounds__(128) void k_tables(const float* __restrict__ rel,
                                                float* __restrict__ Rq, float* __restrict__ Rk,
                                                float* __restrict__ TqT, float* __restrict__ TkT) {
    int bid = blockIdx.x;      // 0..127
    int i = threadIdx.x;       // 0..127
    int p = bid & 63;
    int c = p >> 3, c2 = p & 7;
    const float* ra = (bid < 64) ? (rel + c * 255)  : (rel + (8 + c) * 255);
    const float* rb = (bid < 64) ? (rel + c2 * 255) : (rel + (8 + c2) * 255);
    float tacc = 0.f;
    for (int kk = 0; kk < 128; ++kk) tacc = fmaf(ra[i + kk], rb[i + kk], tacc);
    if (bid < 64) TqT[i * 64 + p] = tacc; else TkT[i * 64 + p] = tacc;
    if (c2 == 0) {
        float racc = 0.f;
        for (int kk = 0; kk < 128; ++kk) racc += ra[i + kk];
        if (bid < 64) Rq[c * 128 + i] = racc; else Rk[c * 128 + i] = racc;
    }
}

// ---------------------------------------------------------------------------
// Analytic score stats per (b,g) — 256 threads; qkv is f16.
// ---------------------------------------------------------------------------
__global__ __launch_bounds__(256) void k_gram(const unsigned short* __restrict__ qkv,
                                              const float* __restrict__ scaleA,
                                              const float* __restrict__ shiftA,
                                              const float* __restrict__ Rq,
                                              const float* __restrict__ Rk,
                                              const float* __restrict__ TqT,
                                              const float* __restrict__ TkT,
                                              double* __restrict__ accS) {
    __shared__ float qs[8][132], ks[8][132];
    __shared__ float redA[4][64][4];
    __shared__ float redB[2][18];
    __shared__ float redC[3];
    int blk = blockIdx.x, b = blk >> 3, g = blk & 7;
    int t = threadIdx.x;
    for (int idx = t; idx < 2048; idx += 256) {
        int cc = idx >> 7, h = idx & 127, o = g * 32 + cc;
        float raw = __half2float(__ushort_as_half(qkv[((size_t)b * CQKV + o) * HLEN + h]));
        float v = raw * scaleA[o] + shiftA[o];
        if (cc < 8) qs[cc][h] = v; else ks[cc - 8][h] = v;
    }
    __syncthreads();
    int lane = t & 63, wv = t >> 6;
    int c = lane >> 3, c2 = lane & 7;
    float gq = 0, gk = 0, tq = 0, tk = 0;
#pragma unroll 4
    for (int ii = 0; ii < 32; ++ii) {
        int i = wv * 32 + ii;
        float a = qs[c][i] * qs[c2][i];
        float e = ks[c][i] * ks[c2][i];
        gq += a; gk += e;
        tq = fmaf(a, TqT[i * 64 + lane], tq);
        tk = fmaf(e, TkT[i * 64 + lane], tk);
    }
    redA[wv][lane][0] = gq; redA[wv][lane][1] = gk;
    redA[wv][lane][2] = tq; redA[wv][lane][3] = tk;

    if (t < 128) {
        int h = t;
        float sqr = 0, skr = 0;
        float sq8l[8], sk8l[8];
#pragma unroll
        for (int c3 = 0; c3 < 8; ++c3) {
            float q0 = qs[c3][h], k0 = ks[c3][h];
            sq8l[c3] = q0; sk8l[c3] = k0;
            sqr = fmaf(q0, Rq[c3 * 128 + h], sqr);
            skr = fmaf(k0, Rk[c3 * 128 + h], skr);
        }
#pragma unroll
        for (int off = 1; off < 64; off <<= 1) {
            sqr += __shfl_xor(sqr, off);
            skr += __shfl_xor(skr, off);
#pragma unroll
            for (int c3 = 0; c3 < 8; ++c3) {
                sq8l[c3] += __shfl_xor(sq8l[c3], off);
                sk8l[c3] += __shfl_xor(sk8l[c3], off);
            }
        }
        if (lane == 0) {
            redB[wv][0] = sqr; redB[wv][1] = skr;
#pragma unroll
            for (int c3 = 0; c3 < 8; ++c3) {
                redB[wv][2 + c3]  = sq8l[c3];
                redB[wv][10 + c3] = sk8l[c3];
            }
        }
    }
    __syncthreads();
    if (t < 64) {
        float Gq = redA[0][t][0] + redA[1][t][0] + redA[2][t][0] + redA[3][t][0];
        float Gk = redA[0][t][1] + redA[1][t][1] + redA[2][t][1] + redA[3][t][1];
        float Tq = redA[0][t][2] + redA[1][t][2] + redA[2][t][2] + redA[3][t][2];
        float Tk = redA[0][t][3] + redA[1][t][3] + redA[2][t][3] + redA[3][t][3];
        float ssqk = Gq * Gk;
#pragma unroll
        for (int off = 1; off < 64; off <<= 1) {
            ssqk += __shfl_xor(ssqk, off);
            Tq   += __shfl_xor(Tq, off);
            Tk   += __shfl_xor(Tk, off);
        }
        if (t == 0) { redC[0] = ssqk; redC[1] = Tq; redC[2] = Tk; }
    }
    __syncthreads();
    if (t == 0) {
        float sqr = redB[0][0] + redB[1][0];
        float skr = redB[0][1] + redB[1][1];
        float sqk = 0;
#pragma unroll
        for (int c3 = 0; c3 < 8; ++c3)
            sqk += (redB[0][2 + c3] + redB[1][2 + c3]) * (redB[0][10 + c3] + redB[1][10 + c3]);
        atomicAdd(&accS[g * 2 + 0], (double)sqk);
        atomicAdd(&accS[g * 2 + 1], (double)redC[0]);
        atomicAdd(&accS[(8 + g) * 2 + 0], (double)(F_QR * sqr));
        atomicAdd(&accS[(8 + g) * 2 + 1], (double)(F_QR * F_QR * redC[1]));
        atomicAdd(&accS[(16 + g) * 2 + 0], (double)(F_KR * skr));
        atomicAdd(&accS[(16 + g) * 2 + 1], (double)(F_KR * F_KR * redC[2]));
    }
}

__global__ void k_sfin(const double* __restrict__ accS,
                       const float* __restrict__ gs, const float* __restrict__ bs,
                       float* __restrict__ scaleS, float* __restrict__ shiftS) {
    int c = threadIdx.x;
    if (c < 24) {
        double cnt  = 512.0 * 128.0 * 128.0;
        double mean = accS[c * 2] / cnt;
        double var  = accS[c * 2 + 1] / cnt - mean * mean;
        float sc = gs[c] * rsqrtf((float)var + EPS);
        scaleS[c] = sc;
        shiftS[c] = bs[c] - (float)mean * sc;
    }
}

// ---------------------------------------------------------------------------
// Attention — fragment-native, f16 qkv/so. __launch_bounds__(256) with NO
// min-waves arg: (256,4) acted as an occupancy cap (42% ≈ 4 blocks) while
// LDS (25.1KB -> 6 blocks) and VGPR (64 -> 8-wave class) permit 6 blocks.
// (256,6) is known-bad: allocator crushed VGPR to 40 -> 600MB spill I/O.
// ---------------------------------------------------------------------------
__global__ __launch_bounds__(256) void k_attn(const unsigned short* __restrict__ qkv,
                                              const float* __restrict__ scaleA,
                                              const float* __restrict__ shiftA,
                                              const float* __restrict__ rel,
                                              const float* __restrict__ scaleS,
                                              const float* __restrict__ shiftS,
                                              unsigned short* __restrict__ so,
                                              double* __restrict__ accF) {
    __shared__ unsigned short qT[128][8];
    __shared__ unsigned short kF[128][8];
    __shared__ unsigned short vB[16][136];
    __shared__ unsigned short rqT[255][8];
    __shared__ unsigned short rkT[255][8];
    __shared__ unsigned short rvA[255][8];
    __shared__ unsigned short rvB[255][8];
    __shared__ float accL[32][2];
    int blk = blockIdx.x, b = blk >> 3, g = blk & 7;
    int t = threadIdx.x;
    if (t < 32) { accL[t][0] = 0.f; accL[t][1] = 0.f; }

    // ---- staging: qkv (f16) via uint2, affine in half2 domain ----
#pragma unroll
    for (int it = 0; it < 4; ++it) {
        int idx = it * 256 + t;
        int cc = idx >> 5;
        int h4 = (idx & 31) << 2;
        int o = g * 32 + cc;
        uint2 v4 = *(const uint2*)(qkv + ((size_t)b * CQKV + o) * HLEN + h4);
        __half2 sc2 = __float2half2_rn(scaleA[o]);
        __half2 sh2 = __float2half2_rn(shiftA[o]);
        __half2 va = __hfma2(*(__half2*)&v4.x, sc2, sh2);
        __half2 vb2 = __hfma2(*(__half2*)&v4.y, sc2, sh2);
        unsigned ua = *(unsigned*)&va, ub = *(unsigned*)&vb2;
        if (cc < 8) {
            qT[h4][cc]     = (unsigned short)(ua & 0xffff);
            qT[h4 + 1][cc] = (unsigned short)(ua >> 16);
            qT[h4 + 2][cc] = (unsigned short)(ub & 0xffff);
            qT[h4 + 3][cc] = (unsigned short)(ub >> 16);
        } else if (cc < 16) {
            kF[h4][cc - 8]     = (unsigned short)(ua & 0xffff);
            kF[h4 + 1][cc - 8] = (unsigned short)(ua >> 16);
            kF[h4 + 2][cc - 8] = (unsigned short)(ub & 0xffff);
            kF[h4 + 3][cc - 8] = (unsigned short)(ub >> 16);
        } else {
            uint2 pk; pk.x = ua; pk.y = ub;
            *(uint2*)&vB[cc - 16][h4] = pk;
        }
    }
    // ---- staging: rel via float4 ----
#pragma unroll
    for (int it = 0; it < 8; ++it) {
        int idx = it * 256 + t;
        if (idx < 2040) {
            float4 v = *(const float4*)(rel + (size_t)idx * 4);
            float vv[4] = {v.x, v.y, v.z, v.w};
#pragma unroll
            for (int e = 0; e < 4; ++e) {
                int lin = idx * 4 + e;
                int r = lin / 255;
                int d = lin - r * 255;
                unsigned short us = f2h(vv[e]);
                if (r < 8)       rqT[d][r] = us;
                else if (r < 16) rkT[d][r - 8] = us;
                else if (r < 24) rvA[d][r - 16] = us;
                else             rvB[d][r - 24] = us;
            }
        }
    }
    __syncthreads();

    float cA = scaleS[g], cB = F_QR * scaleS[8 + g], cC = F_KR * scaleS[16 + g];
    float shsum = shiftS[g] + shiftS[8 + g] + shiftS[16 + g];

    int w = t >> 6, l = t & 63;
    int lr = l & 15, lh = l >> 4;
    int i0 = w * 32 + lr;

    half2v q2[2][4];
    {
        uint4 qv0 = *(const uint4*)&qT[i0][0];
        uint4 qv1 = *(const uint4*)&qT[i0 + 16][0];
        q2[0][0] = *(half2v*)&qv0.x; q2[0][1] = *(half2v*)&qv0.y;
        q2[0][2] = *(half2v*)&qv0.z; q2[0][3] = *(half2v*)&qv0.w;
        q2[1][0] = *(half2v*)&qv1.x; q2[1][1] = *(half2v*)&qv1.y;
        q2[1][2] = *(half2v*)&qv1.z; q2[1][3] = *(half2v*)&qv1.w;
    }

    float p0[32], p1[32];
    float rm0 = -1e30f, rm1 = -1e30f;
#pragma unroll
    for (int ks = 0; ks < 4; ++ks) {
#pragma unroll
        for (int e = 0; e < 8; ++e) {
            int j = ks * 32 + lh * 8 + e;
            uint4 kv = *(const uint4*)&kF[j][0];
            half2v* k2p = (half2v*)&kv;
#pragma unroll
            for (int it2 = 0; it2 < 2; ++it2) {
                int i = i0 + it2 * 16;
                uint4 rq = *(const uint4*)&rqT[i - j + 127][0];
                uint4 rk = *(const uint4*)&rkT[j - i + 127][0];
                half2v* rq2p = (half2v*)&rq;
                half2v* rk2p = (half2v*)&rk;
#ifdef HAVE_FDOT2
                float qk = __builtin_amdgcn_fdot2(q2[it2][0], k2p[0],
                           __builtin_amdgcn_fdot2(q2[it2][1], k2p[1],
                           __builtin_amdgcn_fdot2(q2[it2][2], k2p[2],
                           __builtin_amdgcn_fdot2(q2[it2][3], k2p[3], 0.f, false), false), false), false);
                float qr = __builtin_amdgcn_fdot2(q2[it2][0], rq2p[0],
                           __builtin_amdgcn_fdot2(q2[it2][1], rq2p[1],
                           __builtin_amdgcn_fdot2(q2[it2][2], rq2p[2],
                           __builtin_amdgcn_fdot2(q2[it2][3], rq2p[3], 0.f, false), false), false), false);
                float kr = __builtin_amdgcn_fdot2(k2p[0], rk2p[0],
                           __builtin_amdgcn_fdot2(k2p[1], rk2p[1],
                           __builtin_amdgcn_fdot2(k2p[2], rk2p[2],
                           __builtin_amdgcn_fdot2(k2p[3], rk2p[3], 0.f, false), false), false), false);
#else
                __half2* qh = (__half2*)&q2[it2][0];
                __half2* kk2 = (__half2*)&kv;
                __half2* rq2 = (__half2*)&rq;
                __half2* rk2 = (__half2*)&rk;
                __half2 hqk = __hfma2(qh[0], kk2[0], __hfma2(qh[1], kk2[1],
                              __hfma2(qh[2], kk2[2], __hmul2(qh[3], kk2[3]))));
                __half2 hqr = __hfma2(qh[0], rq2[0], __hfma2(qh[1], rq2[1],
                              __hfma2(qh[2], rq2[2], __hmul2(qh[3], rq2[3]))));
                __half2 hkr = __hfma2(kk2[0], rk2[0], __hfma2(kk2[1], rk2[1],
                              __hfma2(kk2[2], rk2[2], __hmul2(kk2[3], rk2[3]))));
                float qk = __low2float(hqk) + __high2float(hqk);
                float qr = __low2float(hqr) + __high2float(hqr);
                float kr = __low2float(hkr) + __high2float(hkr);
#endif
                float s = fmaf(qk, cA, fmaf(qr, cB, fmaf(kr, cC, shsum)));
                if (it2 == 0) { p0[ks * 8 + e] = s; rm0 = fmaxf(rm0, s); }
                else          { p1[ks * 8 + e] = s; rm1 = fmaxf(rm1, s); }
            }
        }
    }
    rm0 = fmaxf(rm0, __shfl_xor(rm0, 16)); rm0 = fmaxf(rm0, __shfl_xor(rm0, 32));
    rm1 = fmaxf(rm1, __shfl_xor(rm1, 16)); rm1 = fmaxf(rm1, __shfl_xor(rm1, 32));
    float rs0 = 0.f, rs1 = 0.f;
#pragma unroll
    for (int kk = 0; kk < 32; ++kk) {
        p0[kk] = __expf(p0[kk] - rm0); rs0 += p0[kk];
        p1[kk] = __expf(p1[kk] - rm1); rs1 += p1[kk];
    }
    rs0 += __shfl_xor(rs0, 16); rs0 += __shfl_xor(rs0, 32);
    rs1 += __shfl_xor(rs1, 16); rs1 += __shfl_xor(rs1, 32);
    float rn0 = 1.f / rs0, rn1 = 1.f / rs1;

    // ---- sve: raw-exp f16 accumulation ----
    __half2 accA2[8], accB2[8];
#pragma unroll
    for (int m = 0; m < 8; ++m) {
        accA2[m] = __floats2half2_rn(0.f, 0.f);
        accB2[m] = __floats2half2_rn(0.f, 0.f);
    }
#pragma unroll
    for (int ks = 0; ks < 4; ++ks) {
#pragma unroll
        for (int e = 0; e < 8; ++e) {
            int j = ks * 32 + lh * 8 + e;
            {
                int d = i0 - j + 127;
                __half2 p2 = __float2half2_rn(p0[ks * 8 + e]);
                uint4 ra = *(const uint4*)&rvA[d][0];
                uint4 rb = *(const uint4*)&rvB[d][0];
                __half2* ra2 = (__half2*)&ra;
                __half2* rb2 = (__half2*)&rb;
                accA2[0] = __hfma2(p2, ra2[0], accA2[0]);
                accA2[1] = __hfma2(p2, ra2[1], accA2[1]);
                accA2[2] = __hfma2(p2, ra2[2], accA2[2]);
                accA2[3] = __hfma2(p2, ra2[3], accA2[3]);
                accA2[4] = __hfma2(p2, rb2[0], accA2[4]);
                accA2[5] = __hfma2(p2, rb2[1], accA2[5]);
                accA2[6] = __hfma2(p2, rb2[2], accA2[6]);
                accA2[7] = __hfma2(p2, rb2[3], accA2[7]);
            }
            {
                int d = i0 + 16 - j + 127;
                __half2 p2 = __float2half2_rn(p1[ks * 8 + e]);
                uint4 ra = *(const uint4*)&rvA[d][0];
                uint4 rb = *(const uint4*)&rvB[d][0];
                __half2* ra2 = (__half2*)&ra;
                __half2* rb2 = (__half2*)&rb;
                accB2[0] = __hfma2(p2, ra2[0], accB2[0]);
                accB2[1] = __hfma2(p2, ra2[1], accB2[1]);
                accB2[2] = __hfma2(p2, ra2[2], accB2[2]);
                accB2[3] = __hfma2(p2, ra2[3], accB2[3]);
                accB2[4] = __hfma2(p2, rb2[0], accB2[4]);
                accB2[5] = __hfma2(p2, rb2[1], accB2[5]);
                accB2[6] = __hfma2(p2, rb2[2], accB2[6]);
                accB2[7] = __hfma2(p2, rb2[3], accB2[7]);
            }
        }
    }
#pragma unroll
    for (int m = 0; m < 8; ++m) {
        unsigned ua = *(unsigned*)&accA2[m];
        unsigned t1 = __shfl_xor(ua, 16);
        accA2[m] = __hadd2(accA2[m], *(__half2*)&t1);
        ua = *(unsigned*)&accA2[m];
        t1 = __shfl_xor(ua, 32);
        accA2[m] = __hadd2(accA2[m], *(__half2*)&t1);
        unsigned ub = *(unsigned*)&accB2[m];
        unsigned t2 = __shfl_xor(ub, 16);
        accB2[m] = __hadd2(accB2[m], *(__half2*)&t2);
        ub = *(unsigned*)&accB2[m];
        t2 = __shfl_xor(ub, 32);
        accB2[m] = __hadd2(accB2[m], *(__half2*)&t2);
    }
    {
        float sce0 = F_SVE * rn0, sce1 = F_SVE * rn1;
        float s_c[4], ss_c[4];
#pragma unroll
        for (int cc = 0; cc < 4; ++cc) {
            int c = lh * 4 + cc;
            __half2 ha = accA2[c >> 1];
            __half2 hb = accB2[c >> 1];
            float v0 = ((c & 1) ? __high2float(ha) : __low2float(ha)) * sce0;
            float v1 = ((c & 1) ? __high2float(hb) : __low2float(hb)) * sce1;
            size_t base = ((size_t)b * CQKV + g * 32 + 2 * c + 1) * HLEN;
            so[base + i0]      = f2h(v0);
            so[base + i0 + 16] = f2h(v1);
            s_c[cc]  = v0 + v1;
            ss_c[cc] = v0 * v0 + v1 * v1;
        }
#pragma unroll
        for (int off = 1; off < 16; off <<= 1) {
#pragma unroll
            for (int cc = 0; cc < 4; ++cc) {
                s_c[cc]  += __shfl_xor(s_c[cc], off);
                ss_c[cc] += __shfl_xor(ss_c[cc], off);
            }
        }
        if (lr == 0) {
#pragma unroll
            for (int cc = 0; cc < 4; ++cc) {
                int c = lh * 4 + cc;
                atomicAdd(&accL[2 * c + 1][0], s_c[cc]);
                atomicAdd(&accL[2 * c + 1][1], ss_c[cc]);
            }
        }
    }

    // ---- pack P*rn into A-fragment registers ----
    unsigned ph[32];
#pragma unroll
    for (int ks = 0; ks < 4; ++ks) {
#pragma unroll
        for (int e2 = 0; e2 < 4; ++e2) {
            __half2 h0 = __floats2half2_rn(p0[ks * 8 + 2 * e2] * rn0,
                                           p0[ks * 8 + 2 * e2 + 1] * rn0);
            __half2 h1 = __floats2half2_rn(p1[ks * 8 + 2 * e2] * rn1,
                                           p1[ks * 8 + 2 * e2 + 1] * rn1);
            ph[ks * 4 + e2]      = *(unsigned*)&h0;
            ph[16 + ks * 4 + e2] = *(unsigned*)&h1;
        }
    }

    // ---- sv via MFMA (A direct from registers) + fused stats ----
    {
        float s0 = 0.f, ss0 = 0.f;
#pragma unroll
        for (int it2 = 0; it2 < 2; ++it2) {
            int itile = w * 2 + it2;
            float4v acc = {0.f, 0.f, 0.f, 0.f};
#pragma unroll
            for (int ks = 0; ks < 4; ++ks) {
                half8v af = *(half8v*)&ph[it2 * 16 + ks * 4];
                half8v bf = *(const half8v*)&vB[lr][ks * 32 + lh * 8];
                acc = __builtin_amdgcn_mfma_f32_16x16x32_f16(af, bf, acc, 0, 0, 0);
            }
            int oc = g * 32 + 2 * lr;
            float ox = acc[0] * F_SV, oy = acc[1] * F_SV;
            float oz = acc[2] * F_SV, ow = acc[3] * F_SV;
            __half2 o01 = __floats2half2_rn(ox, oy);
            __half2 o23 = __floats2half2_rn(oz, ow);
            uint2 pk; pk.x = *(unsigned*)&o01; pk.y = *(unsigned*)&o23;
            *(uint2*)(so + ((size_t)b * CQKV + oc) * HLEN + itile * 16 + lh * 4) = pk;
            s0  += ox + oy + oz + ow;
            ss0 += ox * ox + oy * oy + oz * oz + ow * ow;
        }
        s0  += __shfl_xor(s0, 16);  s0  += __shfl_xor(s0, 32);
        ss0 += __shfl_xor(ss0, 16); ss0 += __shfl_xor(ss0, 32);
        if (lh == 0) {
            atomicAdd(&accL[2 * lr][0], s0);
            atomicAdd(&accL[2 * lr][1], ss0);
        }
    }
    __syncthreads();
    if (t < 32) {
        int o = g * 32 + t;
        atomicAdd(&accF[(size_t)o * 2 + 0], (double)accL[t][0]);
        atomicAdd(&accF[(size_t)o * 2 + 1], (double)accL[t][1]);
    }
}

// ---------------------------------------------------------------------------
// Final affine + pair-sum + transpose (f16 in, f32 out)
// ---------------------------------------------------------------------------
__global__ __launch_bounds__(256) void k_out(const unsigned short* __restrict__ so,
                                             const float* __restrict__ scale,
                                             const float* __restrict__ shift,
                                             float* __restrict__ out) {
    int b = blockIdx.x, n = b >> 6, wi = b & 63;
    int t = threadIdx.x;
    int h4  = (t & 31) << 2;
    int oc0 = (t >> 5) << 4;
    for (int k = 0; k < 16; ++k) {
        int oc = oc0 + k;
        uint2 u0 = *(const uint2*)(so + ((size_t)b * CQKV + 2 * oc) * HLEN + h4);
        uint2 u1 = *(const uint2*)(so + ((size_t)b * CQKV + 2 * oc + 1) * HLEN + h4);
        __half2 a0 = *(__half2*)&u0.x, a1 = *(__half2*)&u0.y;
        __half2 b0 = *(__half2*)&u1.x, b1 = *(__half2*)&u1.y;
        float s0 = scale[2 * oc], f0 = shift[2 * oc];
        float s1 = scale[2 * oc + 1], f1 = shift[2 * oc + 1];
        float4 o4;
        o4.x = fmaf(__low2float(a0),  s0, f0) + fmaf(__low2float(b0),  s1, f1);
        o4.y = fmaf(__high2float(a0), s0, f0) + fmaf(__high2float(b0), s1, f1);
        o4.z = fmaf(__low2float(a1),  s0, f0) + fmaf(__low2float(b1),  s1, f1);
        o4.w = fmaf(__high2float(a1), s0, f0) + fmaf(__high2float(b1), s1, f1);
        *(float4*)(out + (((size_t)n * 128 + oc) * 64 + wi) * HLEN + h4) = o4;
    }
}

extern "C" void kernel_launch(void* const* d_in, const int* in_sizes, int n_in,
                              void* d_out, int out_size, void* d_ws, size_t ws_size,
                              hipStream_t stream) {
    const float* x   = (const float*)d_in[0];
    const float* w   = (const float*)d_in[1];
    const float* g1  = (const float*)d_in[2];
    const float* b1  = (const float*)d_in[3];
    const float* g2  = (const float*)d_in[4];
    const float* b2  = (const float*)d_in[5];
    const float* gs  = (const float*)d_in[6];
    const float* bs  = (const float*)d_in[7];
    const float* go  = (const float*)d_in[8];
    const float* bo  = (const float*)d_in[9];
    const float* rel = (const float*)d_in[10];
    float* out = (float*)d_out;

    unsigned short* qkv = (unsigned short*)d_ws;        // 16,777,216 f16
    unsigned short* so  = qkv + (size_t)16777216;       // 16,777,216 f16
    double* accA   = (double*)(so + (size_t)16777216);  // 512 d
    double* accS   = accA + 512;                        // 48 d
    double* accF   = accS + 48;                         // 512 d
    float*  scaleA = (float*)(accF + 512);
    float*  shiftA = scaleA + 256;
    float*  scaleS = shiftA + 256;                      // 24
    float*  shiftS = scaleS + 24;
    float*  scaleF = shiftS + 24;                       // 256
    float*  shiftF = scaleF + 256;
    float*  Rq     = shiftF + 256;                      // 1024
    float*  Rk     = Rq + 1024;                         // 1024
    float*  TqT    = Rk + 1024;                         // 8192
    float*  TkT    = TqT + 8192;                        // 8192

    hipMemsetAsync(accA, 0, (512 + 48 + 512) * sizeof(double), stream);

    k_qkv<<<1024, 256, 0, stream>>>(x, w, qkv, accA);
    k_tables<<<128, 128, 0, stream>>>(rel, Rq, Rk, TqT, TkT);
    k_finA<<<1, 256, 0, stream>>>(accA, g1, g2, b2, scaleA, shiftA);
    k_gram<<<4096, 256, 0, stream>>>(qkv, scaleA, shiftA, Rq, Rk, TqT, TkT, accS);
    k_sfin<<<1, 32, 0, stream>>>(accS, gs, bs, scaleS, shiftS);
    k_attn<<<4096, 256, 0, stream>>>(qkv, scaleA, shiftA, rel, scaleS, shiftS, so, accF);
    k_finF<<<1, 256, 0, stream>>>(accF, go, bo, scaleF, shiftF);
    k_out<<<512, 256, 0, stream>>>(so, scaleF, shiftF, out);
}

// Round 16
// 307.223 us; speedup vs baseline: 1.2062x; 1.0081x over previous
//
#include <hip/hip_runtime.h>
#include <hip/hip_fp16.h>
#include <math.h>

#define B_TOT 512
#define CQKV  256
#define CIN   128
#define HLEN  128

static constexpr float F_QR = 0.3f, F_KR = 0.3f, F_SV = 0.5f, F_SVE = 0.3f;
static constexpr float EPS = 1e-5f;

typedef __attribute__((ext_vector_type(8))) short short8v;
typedef __attribute__((ext_vector_type(8))) _Float16 half8v;
typedef __attribute__((ext_vector_type(2))) _Float16 half2v;
typedef __attribute__((ext_vector_type(4))) float float4v;

#if __has_builtin(__builtin_amdgcn_fdot2)
#define HAVE_FDOT2 1
#endif

__device__ __forceinline__ unsigned short f2bf(float f) {
    unsigned u = __float_as_uint(f);
    unsigned r = u + 0x7fffu + ((u >> 16) & 1u);
    return (unsigned short)(r >> 16);
}
__device__ __forceinline__ unsigned short f2h(float f) {
    return __half_as_ushort(__float2half(f));
}

// ---------------------------------------------------------------------------
// Kernel 1 (MFMA): qkv GEMM + fused per-channel raw stats.
// C-write via LDS transpose (Xs reused): coalesced uint4 stores, no 2x
// write amplification from scalar u16 scatter.
// ---------------------------------------------------------------------------
__global__ __launch_bounds__(256, 3) void k_qkv(const float* __restrict__ x,
                                                const float* __restrict__ w,
                                                unsigned short* __restrict__ qkv,
                                                double* __restrict__ accA) {
    __shared__ unsigned short As[64][136];
    __shared__ unsigned short Xs[17408];   // GEMM view: [m][64]; store view: [64][272]
    __shared__ float wsum[64][2];
    int bid = blockIdx.x;
    int n   = bid >> 7;
    int sub = bid & 127;
    int mt  = sub >> 2;
    int ot  = sub & 3;
    int m0  = mt << 8;
    int o0  = ot << 6;
    int t   = threadIdx.x;

    if (t < 64) { wsum[t][0] = 0.f; wsum[t][1] = 0.f; }

#pragma unroll
    for (int it = 0; it < 8; ++it) {
        int idx = it * 256 + t;
        int o = idx >> 5, c4 = (idx & 31) << 2;
        float4 wv = *(const float4*)(w + (size_t)(o0 + o) * CIN + c4);
        As[o][c4 + 0] = f2bf(wv.x);
        As[o][c4 + 1] = f2bf(wv.y);
        As[o][c4 + 2] = f2bf(wv.z);
        As[o][c4 + 3] = f2bf(wv.w);
    }

    const float* xn = x + (size_t)n * CIN * 8192 + m0;

    int wv_ = t >> 6, l = t & 63;
    int lr = l & 15, lh = l >> 4;
    int mw = wv_ << 6;

    float4v acc[4][4];
#pragma unroll
    for (int a = 0; a < 4; ++a)
#pragma unroll
        for (int b2 = 0; b2 < 4; ++b2) acc[a][b2] = (float4v){0.f, 0.f, 0.f, 0.f};

    for (int s = 0; s < 2; ++s) {
        int c0 = s << 6;
        __syncthreads();
#pragma unroll
        for (int it = 0; it < 16; ++it) {
            int c  = (it << 2) + (t >> 6);
            int m4 = (t & 63) << 2;
            float4 xv = *(const float4*)(xn + (size_t)(c0 + c) * 8192 + m4);
            float vals[4] = {xv.x, xv.y, xv.z, xv.w};
#pragma unroll
            for (int j = 0; j < 4; ++j) {
                int m = m4 + j;
                int cs = (((c >> 3) ^ ((m >> 2) & 7)) << 3) | (c & 7);
                Xs[m * 64 + cs] = f2bf(vals[j]);
            }
        }
        __syncthreads();
#pragma unroll
        for (int ks = 0; ks < 2; ++ks) {
            short8v af[4], bf[4];
#pragma unroll
            for (int a = 0; a < 4; ++a)
                af[a] = *(const short8v*)&As[a * 16 + lr][c0 + ks * 32 + lh * 8];
#pragma unroll
            for (int b2 = 0; b2 < 4; ++b2) {
                int m  = mw + b2 * 16 + lr;
                int cb = (ks * 4 + lh) ^ ((m >> 2) & 7);
                bf[b2] = *(const short8v*)&Xs[m * 64 + (cb << 3)];
            }
#pragma unroll
            for (int a = 0; a < 4; ++a)
#pragma unroll
                for (int b2 = 0; b2 < 4; ++b2)
                    acc[a][b2] = __builtin_amdgcn_mfma_f32_16x16x32_bf16(
                        af[a], bf[b2], acc[a][b2], 0, 0, 0);
        }
    }

    // ---- C-write: transpose through Xs, then coalesced uint4 stores ----
    __syncthreads();
#pragma unroll
    for (int a = 0; a < 4; ++a)
#pragma unroll
        for (int b2 = 0; b2 < 4; ++b2) {
            int ml = mw + b2 * 16 + lr;
#pragma unroll
            for (int r = 0; r < 4; ++r) {
                int o = a * 16 + lh * 4 + r;
                Xs[o * 272 + ml] = f2h(acc[a][b2][r]);
            }
        }
    __syncthreads();
    {
        int bb0 = n * 64 + (m0 >> 7);
#pragma unroll
        for (int it = 0; it < 8; ++it) {
            int u = it * 256 + t;
            int row = u >> 5, cu = u & 31;
            int ml0 = cu * 8;
            int seg = ml0 >> 7, hm = ml0 & 127;
            uint4 v = *(uint4*)&Xs[row * 272 + ml0];
            *(uint4*)(qkv + ((size_t)(bb0 + seg) * CQKV + o0 + row) * HLEN + hm) = v;
        }
    }

    // ---- fused raw-channel stats (registers only) ----
#pragma unroll
    for (int a = 0; a < 4; ++a) {
#pragma unroll
        for (int r = 0; r < 4; ++r) {
            float s = 0.f, ss = 0.f;
#pragma unroll
            for (int b2 = 0; b2 < 4; ++b2) {
                float v = acc[a][b2][r];
                s += v; ss += v * v;
            }
#pragma unroll
            for (int off = 1; off < 16; off <<= 1) {
                s  += __shfl_xor(s, off);
                ss += __shfl_xor(ss, off);
            }
            if (lr == 0) {
                int ol = a * 16 + lh * 4 + r;
                atomicAdd(&wsum[ol][0], s);
                atomicAdd(&wsum[ol][1], ss);
            }
        }
    }
    __syncthreads();
    if (t < 64) {
        atomicAdd(&accA[(size_t)(o0 + t) * 2 + 0], (double)wsum[t][0]);
        atomicAdd(&accA[(size_t)(o0 + t) * 2 + 1], (double)wsum[t][1]);
    }
}

__global__ void k_finA(const double* __restrict__ accA,
                       const float* __restrict__ g1, const float* __restrict__ g2,
                       const float* __restrict__ b2,
                       float* __restrict__ scaleA, float* __restrict__ shiftA) {
    int o = threadIdx.x;
    double cnt  = 65536.0;
    double mean = accA[o * 2] / cnt;
    double var  = accA[o * 2 + 1] / cnt - mean * mean;
    float r1 = rsqrtf((float)var + EPS);
    float v2 = g1[o] * g1[o] * (float)var * r1 * r1;
    float sc = g1[o] * g2[o] * r1 * rsqrtf(v2 + EPS);
    scaleA[o] = sc;
    shiftA[o] = b2[o] - (float)mean * sc;
}

__global__ void k_finF(const double* __restrict__ accF,
                       const float* __restrict__ go, const float* __restrict__ bo,
                       float* __restrict__ scaleF, float* __restrict__ shiftF) {
    int o = threadIdx.x;
    double cnt  = 65536.0;
    double mean = accF[o * 2] / cnt;
    double var  = accF[o * 2 + 1] / cnt - mean * mean;
    float sc = go[o] * rsqrtf((float)var + EPS);
    scaleF[o] = sc;
    shiftF[o] = bo[o] - (float)mean * sc;
}

// ---------------------------------------------------------------------------
// Tables for analytic score stats (f32, for k_gram).
// ---------------------------------------------------------------------------
__global__ __launch_bounds__(128) void k_tables(const float* __restrict__ rel,
                                                float* __restrict__ Rq, float* __restrict__ Rk,
                                                float* __restrict__ TqT, float* __restrict__ TkT) {
    int bid = blockIdx.x;      // 0..127
    int i = threadIdx.x;       // 0..127
    int p = bid & 63;
    int c = p >> 3, c2 = p & 7;
    const float* ra = (bid < 64) ? (rel + c * 255)  : (rel + (8 + c) * 255);
    const float* rb = (bid < 64) ? (rel + c2 * 255) : (rel + (8 + c2) * 255);
    float tacc = 0.f;
    for (int kk = 0; kk < 128; ++kk) tacc = fmaf(ra[i + kk], rb[i + kk], tacc);
    if (bid < 64) TqT[i * 64 + p] = tacc; else TkT[i * 64 + p] = tacc;
    if (c2 == 0) {
        float racc = 0.f;
        for (int kk = 0; kk < 128; ++kk) racc += ra[i + kk];
        if (bid < 64) Rq[c * 128 + i] = racc; else Rk[c * 128 + i] = racc;
    }
}

// ---------------------------------------------------------------------------
// Analytic score stats per (b,g) — 256 threads; vectorized f16 staging.
// ---------------------------------------------------------------------------
__global__ __launch_bounds__(256) void k_gram(const unsigned short* __restrict__ qkv,
                                              const float* __restrict__ scaleA,
                                              const float* __restrict__ shiftA,
                                              const float* __restrict__ Rq,
                                              const float* __restrict__ Rk,
                                              const float* __restrict__ TqT,
                                              const float* __restrict__ TkT,
                                              double* __restrict__ accS) {
    __shared__ float qs[8][132], ks[8][132];
    __shared__ float redA[4][64][4];
    __shared__ float redB[2][18];
    __shared__ float redC[3];
    int blk = blockIdx.x, b = blk >> 3, g = blk & 7;
    int t = threadIdx.x;
    {
        int cc = t >> 4, h8 = (t & 15) * 8, o = g * 32 + cc;
        uint4 raw = *(const uint4*)(qkv + ((size_t)b * CQKV + o) * HLEN + h8);
        float sc = scaleA[o], sh = shiftA[o];
        const unsigned short* rp = (const unsigned short*)&raw;
        float* dst = (cc < 8) ? &qs[cc][0] : &ks[cc - 8][0];
#pragma unroll
        for (int e = 0; e < 8; ++e)
            dst[h8 + e] = fmaf(__half2float(__ushort_as_half(rp[e])), sc, sh);
    }
    __syncthreads();
    int lane = t & 63, wv = t >> 6;
    int c = lane >> 3, c2 = lane & 7;
    float gq = 0, gk = 0, tq = 0, tk = 0;
#pragma unroll 4
    for (int ii = 0; ii < 32; ++ii) {
        int i = wv * 32 + ii;
        float a = qs[c][i] * qs[c2][i];
        float e = ks[c][i] * ks[c2][i];
        gq += a; gk += e;
        tq = fmaf(a, TqT[i * 64 + lane], tq);
        tk = fmaf(e, TkT[i * 64 + lane], tk);
    }
    redA[wv][lane][0] = gq; redA[wv][lane][1] = gk;
    redA[wv][lane][2] = tq; redA[wv][lane][3] = tk;

    if (t < 128) {
        int h = t;
        float sqr = 0, skr = 0;
        float sq8l[8], sk8l[8];
#pragma unroll
        for (int c3 = 0; c3 < 8; ++c3) {
            float q0 = qs[c3][h], k0 = ks[c3][h];
            sq8l[c3] = q0; sk8l[c3] = k0;
            sqr = fmaf(q0, Rq[c3 * 128 + h], sqr);
            skr = fmaf(k0, Rk[c3 * 128 + h], skr);
        }
#pragma unroll
        for (int off = 1; off < 64; off <<= 1) {
            sqr += __shfl_xor(sqr, off);
            skr += __shfl_xor(skr, off);
#pragma unroll
            for (int c3 = 0; c3 < 8; ++c3) {
                sq8l[c3] += __shfl_xor(sq8l[c3], off);
                sk8l[c3] += __shfl_xor(sk8l[c3], off);
            }
        }
        if (lane == 0) {
            redB[wv][0] = sqr; redB[wv][1] = skr;
#pragma unroll
            for (int c3 = 0; c3 < 8; ++c3) {
                redB[wv][2 + c3]  = sq8l[c3];
                redB[wv][10 + c3] = sk8l[c3];
            }
        }
    }
    __syncthreads();
    if (t < 64) {
        float Gq = redA[0][t][0] + redA[1][t][0] + redA[2][t][0] + redA[3][t][0];
        float Gk = redA[0][t][1] + redA[1][t][1] + redA[2][t][1] + redA[3][t][1];
        float Tq = redA[0][t][2] + redA[1][t][2] + redA[2][t][2] + redA[3][t][2];
        float Tk = redA[0][t][3] + redA[1][t][3] + redA[2][t][3] + redA[3][t][3];
        float ssqk = Gq * Gk;
#pragma unroll
        for (int off = 1; off < 64; off <<= 1) {
            ssqk += __shfl_xor(ssqk, off);
            Tq   += __shfl_xor(Tq, off);
            Tk   += __shfl_xor(Tk, off);
        }
        if (t == 0) { redC[0] = ssqk; redC[1] = Tq; redC[2] = Tk; }
    }
    __syncthreads();
    if (t == 0) {
        float sqr = redB[0][0] + redB[1][0];
        float skr = redB[0][1] + redB[1][1];
        float sqk = 0;
#pragma unroll
        for (int c3 = 0; c3 < 8; ++c3)
            sqk += (redB[0][2 + c3] + redB[1][2 + c3]) * (redB[0][10 + c3] + redB[1][10 + c3]);
        atomicAdd(&accS[g * 2 + 0], (double)sqk);
        atomicAdd(&accS[g * 2 + 1], (double)redC[0]);
        atomicAdd(&accS[(8 + g) * 2 + 0], (double)(F_QR * sqr));
        atomicAdd(&accS[(8 + g) * 2 + 1], (double)(F_QR * F_QR * redC[1]));
        atomicAdd(&accS[(16 + g) * 2 + 0], (double)(F_KR * skr));
        atomicAdd(&accS[(16 + g) * 2 + 1], (double)(F_KR * F_KR * redC[2]));
    }
}

__global__ void k_sfin(const double* __restrict__ accS,
                       const float* __restrict__ gs, const float* __restrict__ bs,
                       float* __restrict__ scaleS, float* __restrict__ shiftS) {
    int c = threadIdx.x;
    if (c < 24) {
        double cnt  = 512.0 * 128.0 * 128.0;
        double mean = accS[c * 2] / cnt;
        double var  = accS[c * 2 + 1] / cnt - mean * mean;
        float sc = gs[c] * rsqrtf((float)var + EPS);
        scaleS[c] = sc;
        shiftS[c] = bs[c] - (float)mean * sc;
    }
}

// ---------------------------------------------------------------------------
// Attention — fragment-native, f16 qkv/so (round-15, byte-identical).
// ---------------------------------------------------------------------------
__global__ __launch_bounds__(256) void k_attn(const unsigned short* __restrict__ qkv,
                                              const float* __restrict__ scaleA,
                                              const float* __restrict__ shiftA,
                                              const float* __restrict__ rel,
                                              const float* __restrict__ scaleS,
                                              const float* __restrict__ shiftS,
                                              unsigned short* __restrict__ so,
                                              double* __restrict__ accF) {
    __shared__ unsigned short qT[128][8];
    __shared__ unsigned short kF[128][8];
    __shared__ unsigned short vB[16][136];
    __shared__ unsigned short rqT[255][8];
    __shared__ unsigned short rkT[255][8];
    __shared__ unsigned short rvA[255][8];
    __shared__ unsigned short rvB[255][8];
    __shared__ float accL[32][2];
    int blk = blockIdx.x, b = blk >> 3, g = blk & 7;
    int t = threadIdx.x;
    if (t < 32) { accL[t][0] = 0.f; accL[t][1] = 0.f; }

    // ---- staging: qkv (f16) via uint2, affine in half2 domain ----
#pragma unroll
    for (int it = 0; it < 4; ++it) {
        int idx = it * 256 + t;
        int cc = idx >> 5;
        int h4 = (idx & 31) << 2;
        int o = g * 32 + cc;
        uint2 v4 = *(const uint2*)(qkv + ((size_t)b * CQKV + o) * HLEN + h4);
        __half2 sc2 = __float2half2_rn(scaleA[o]);
        __half2 sh2 = __float2half2_rn(shiftA[o]);
        __half2 va = __hfma2(*(__half2*)&v4.x, sc2, sh2);
        __half2 vb2 = __hfma2(*(__half2*)&v4.y, sc2, sh2);
        unsigned ua = *(unsigned*)&va, ub = *(unsigned*)&vb2;
        if (cc < 8) {
            qT[h4][cc]     = (unsigned short)(ua & 0xffff);
            qT[h4 + 1][cc] = (unsigned short)(ua >> 16);
            qT[h4 + 2][cc] = (unsigned short)(ub & 0xffff);
            qT[h4 + 3][cc] = (unsigned short)(ub >> 16);
        } else if (cc < 16) {
            kF[h4][cc - 8]     = (unsigned short)(ua & 0xffff);
            kF[h4 + 1][cc - 8] = (unsigned short)(ua >> 16);
            kF[h4 + 2][cc - 8] = (unsigned short)(ub & 0xffff);
            kF[h4 + 3][cc - 8] = (unsigned short)(ub >> 16);
        } else {
            uint2 pk; pk.x = ua; pk.y = ub;
            *(uint2*)&vB[cc - 16][h4] = pk;
        }
    }
    // ---- staging: rel via float4 ----
#pragma unroll
    for (int it = 0; it < 8; ++it) {
        int idx = it * 256 + t;
        if (idx < 2040) {
            float4 v = *(const float4*)(rel + (size_t)idx * 4);
            float vv[4] = {v.x, v.y, v.z, v.w};
#pragma unroll
            for (int e = 0; e < 4; ++e) {
                int lin = idx * 4 + e;
                int r = lin / 255;
                int d = lin - r * 255;
                unsigned short us = f2h(vv[e]);
                if (r < 8)       rqT[d][r] = us;
                else if (r < 16) rkT[d][r - 8] = us;
                else if (r < 24) rvA[d][r - 16] = us;
                else             rvB[d][r - 24] = us;
            }
        }
    }
    __syncthreads();

    float cA = scaleS[g], cB = F_QR * scaleS[8 + g], cC = F_KR * scaleS[16 + g];
    float shsum = shiftS[g] + shiftS[8 + g] + shiftS[16 + g];

    int w = t >> 6, l = t & 63;
    int lr = l & 15, lh = l >> 4;
    int i0 = w * 32 + lr;

    half2v q2[2][4];
    {
        uint4 qv0 = *(const uint4*)&qT[i0][0];
        uint4 qv1 = *(const uint4*)&qT[i0 + 16][0];
        q2[0][0] = *(half2v*)&qv0.x; q2[0][1] = *(half2v*)&qv0.y;
        q2[0][2] = *(half2v*)&qv0.z; q2[0][3] = *(half2v*)&qv0.w;
        q2[1][0] = *(half2v*)&qv1.x; q2[1][1] = *(half2v*)&qv1.y;
        q2[1][2] = *(half2v*)&qv1.z; q2[1][3] = *(half2v*)&qv1.w;
    }

    float p0[32], p1[32];
    float rm0 = -1e30f, rm1 = -1e30f;
#pragma unroll
    for (int ks = 0; ks < 4; ++ks) {
#pragma unroll
        for (int e = 0; e < 8; ++e) {
            int j = ks * 32 + lh * 8 + e;
            uint4 kv = *(const uint4*)&kF[j][0];
            half2v* k2p = (half2v*)&kv;
#pragma unroll
            for (int it2 = 0; it2 < 2; ++it2) {
                int i = i0 + it2 * 16;
                uint4 rq = *(const uint4*)&rqT[i - j + 127][0];
                uint4 rk = *(const uint4*)&rkT[j - i + 127][0];
                half2v* rq2p = (half2v*)&rq;
                half2v* rk2p = (half2v*)&rk;
#ifdef HAVE_FDOT2
                float qk = __builtin_amdgcn_fdot2(q2[it2][0], k2p[0],
                           __builtin_amdgcn_fdot2(q2[it2][1], k2p[1],
                           __builtin_amdgcn_fdot2(q2[it2][2], k2p[2],
                           __builtin_amdgcn_fdot2(q2[it2][3], k2p[3], 0.f, false), false), false), false);
                float qr = __builtin_amdgcn_fdot2(q2[it2][0], rq2p[0],
                           __builtin_amdgcn_fdot2(q2[it2][1], rq2p[1],
                           __builtin_amdgcn_fdot2(q2[it2][2], rq2p[2],
                           __builtin_amdgcn_fdot2(q2[it2][3], rq2p[3], 0.f, false), false), false), false);
                float kr = __builtin_amdgcn_fdot2(k2p[0], rk2p[0],
                           __builtin_amdgcn_fdot2(k2p[1], rk2p[1],
                           __builtin_amdgcn_fdot2(k2p[2], rk2p[2],
                           __builtin_amdgcn_fdot2(k2p[3], rk2p[3], 0.f, false), false), false), false);
#else
                __half2* qh = (__half2*)&q2[it2][0];
                __half2* kk2 = (__half2*)&kv;
                __half2* rq2 = (__half2*)&rq;
                __half2* rk2 = (__half2*)&rk;
                __half2 hqk = __hfma2(qh[0], kk2[0], __hfma2(qh[1], kk2[1],
                              __hfma2(qh[2], kk2[2], __hmul2(qh[3], kk2[3]))));
                __half2 hqr = __hfma2(qh[0], rq2[0], __hfma2(qh[1], rq2[1],
                              __hfma2(qh[2], rq2[2], __hmul2(qh[3], rq2[3]))));
                __half2 hkr = __hfma2(kk2[0], rk2[0], __hfma2(kk2[1], rk2[1],
                              __hfma2(kk2[2], rk2[2], __hmul2(kk2[3], rk2[3]))));
                float qk = __low2float(hqk) + __high2float(hqk);
                float qr = __low2float(hqr) + __high2float(hqr);
                float kr = __low2float(hkr) + __high2float(hkr);
#endif
                float s = fmaf(qk, cA, fmaf(qr, cB, fmaf(kr, cC, shsum)));
                if (it2 == 0) { p0[ks * 8 + e] = s; rm0 = fmaxf(rm0, s); }
                else          { p1[ks * 8 + e] = s; rm1 = fmaxf(rm1, s); }
            }
        }
    }
    rm0 = fmaxf(rm0, __shfl_xor(rm0, 16)); rm0 = fmaxf(rm0, __shfl_xor(rm0, 32));
    rm1 = fmaxf(rm1, __shfl_xor(rm1, 16)); rm1 = fmaxf(rm1, __shfl_xor(rm1, 32));
    float rs0 = 0.f, rs1 = 0.f;
#pragma unroll
    for (int kk = 0; kk < 32; ++kk) {
        p0[kk] = __expf(p0[kk] - rm0); rs0 += p0[kk];
        p1[kk] = __expf(p1[kk] - rm1); rs1 += p1[kk];
    }
    rs0 += __shfl_xor(rs0, 16); rs0 += __shfl_xor(rs0, 32);
    rs1 += __shfl_xor(rs1, 16); rs1 += __shfl_xor(rs1, 32);
    float rn0 = 1.f / rs0, rn1 = 1.f / rs1;

    // ---- sve: raw-exp f16 accumulation ----
    __half2 accA2[8], accB2[8];
#pragma unroll
    for (int m = 0; m < 8; ++m) {
        accA2[m] = __floats2half2_rn(0.f, 0.f);
        accB2[m] = __floats2half2_rn(0.f, 0.f);
    }
#pragma unroll
    for (int ks = 0; ks < 4; ++ks) {
#pragma unroll
        for (int e = 0; e < 8; ++e) {
            int j = ks * 32 + lh * 8 + e;
            {
                int d = i0 - j + 127;
                __half2 p2 = __float2half2_rn(p0[ks * 8 + e]);
                uint4 ra = *(const uint4*)&rvA[d][0];
                uint4 rb = *(const uint4*)&rvB[d][0];
                __half2* ra2 = (__half2*)&ra;
                __half2* rb2 = (__half2*)&rb;
                accA2[0] = __hfma2(p2, ra2[0], accA2[0]);
                accA2[1] = __hfma2(p2, ra2[1], accA2[1]);
                accA2[2] = __hfma2(p2, ra2[2], accA2[2]);
                accA2[3] = __hfma2(p2, ra2[3], accA2[3]);
                accA2[4] = __hfma2(p2, rb2[0], accA2[4]);
                accA2[5] = __hfma2(p2, rb2[1], accA2[5]);
                accA2[6] = __hfma2(p2, rb2[2], accA2[6]);
                accA2[7] = __hfma2(p2, rb2[3], accA2[7]);
            }
            {
                int d = i0 + 16 - j + 127;
                __half2 p2 = __float2half2_rn(p1[ks * 8 + e]);
                uint4 ra = *(const uint4*)&rvA[d][0];
                uint4 rb = *(const uint4*)&rvB[d][0];
                __half2* ra2 = (__half2*)&ra;
                __half2* rb2 = (__half2*)&rb;
                accB2[0] = __hfma2(p2, ra2[0], accB2[0]);
                accB2[1] = __hfma2(p2, ra2[1], accB2[1]);
                accB2[2] = __hfma2(p2, ra2[2], accB2[2]);
                accB2[3] = __hfma2(p2, ra2[3], accB2[3]);
                accB2[4] = __hfma2(p2, rb2[0], accB2[4]);
                accB2[5] = __hfma2(p2, rb2[1], accB2[5]);
                accB2[6] = __hfma2(p2, rb2[2], accB2[6]);
                accB2[7] = __hfma2(p2, rb2[3], accB2[7]);
            }
        }
    }
#pragma unroll
    for (int m = 0; m < 8; ++m) {
        unsigned ua = *(unsigned*)&accA2[m];
        unsigned t1 = __shfl_xor(ua, 16);
        accA2[m] = __hadd2(accA2[m], *(__half2*)&t1);
        ua = *(unsigned*)&accA2[m];
        t1 = __shfl_xor(ua, 32);
        accA2[m] = __hadd2(accA2[m], *(__half2*)&t1);
        unsigned ub = *(unsigned*)&accB2[m];
        unsigned t2 = __shfl_xor(ub, 16);
        accB2[m] = __hadd2(accB2[m], *(__half2*)&t2);
        ub = *(unsigned*)&accB2[m];
        t2 = __shfl_xor(ub, 32);
        accB2[m] = __hadd2(accB2[m], *(__half2*)&t2);
    }
    {
        float sce0 = F_SVE * rn0, sce1 = F_SVE * rn1;
        float s_c[4], ss_c[4];
#pragma unroll
        for (int cc = 0; cc < 4; ++cc) {
            int c = lh * 4 + cc;
            __half2 ha = accA2[c >> 1];
            __half2 hb = accB2[c >> 1];
            float v0 = ((c & 1) ? __high2float(ha) : __low2float(ha)) * sce0;
            float v1 = ((c & 1) ? __high2float(hb) : __low2float(hb)) * sce1;
            size_t base = ((size_t)b * CQKV + g * 32 + 2 * c + 1) * HLEN;
            so[base + i0]      = f2h(v0);
            so[base + i0 + 16] = f2h(v1);
            s_c[cc]  = v0 + v1;
            ss_c[cc] = v0 * v0 + v1 * v1;
        }
#pragma unroll
        for (int off = 1; off < 16; off <<= 1) {
#pragma unroll
            for (int cc = 0; cc < 4; ++cc) {
                s_c[cc]  += __shfl_xor(s_c[cc], off);
                ss_c[cc] += __shfl_xor(ss_c[cc], off);
            }
        }
        if (lr == 0) {
#pragma unroll
            for (int cc = 0; cc < 4; ++cc) {
                int c = lh * 4 + cc;
                atomicAdd(&accL[2 * c + 1][0], s_c[cc]);
                atomicAdd(&accL[2 * c + 1][1], ss_c[cc]);
            }
        }
    }

    // ---- pack P*rn into A-fragment registers ----
    unsigned ph[32];
#pragma unroll
    for (int ks = 0; ks < 4; ++ks) {
#pragma unroll
        for (int e2 = 0; e2 < 4; ++e2) {
            __half2 h0 = __floats2half2_rn(p0[ks * 8 + 2 * e2] * rn0,
                                           p0[ks * 8 + 2 * e2 + 1] * rn0);
            __half2 h1 = __floats2half2_rn(p1[ks * 8 + 2 * e2] * rn1,
                                           p1[ks * 8 + 2 * e2 + 1] * rn1);
            ph[ks * 4 + e2]      = *(unsigned*)&h0;
            ph[16 + ks * 4 + e2] = *(unsigned*)&h1;
        }
    }

    // ---- sv via MFMA (A direct from registers) + fused stats ----
    {
        float s0 = 0.f, ss0 = 0.f;
#pragma unroll
        for (int it2 = 0; it2 < 2; ++it2) {
            int itile = w * 2 + it2;
            float4v acc = {0.f, 0.f, 0.f, 0.f};
#pragma unroll
            for (int ks = 0; ks < 4; ++ks) {
                half8v af = *(half8v*)&ph[it2 * 16 + ks * 4];
                half8v bf = *(const half8v*)&vB[lr][ks * 32 + lh * 8];
                acc = __builtin_amdgcn_mfma_f32_16x16x32_f16(af, bf, acc, 0, 0, 0);
            }
            int oc = g * 32 + 2 * lr;
            float ox = acc[0] * F_SV, oy = acc[1] * F_SV;
            float oz = acc[2] * F_SV, ow = acc[3] * F_SV;
            __half2 o01 = __floats2half2_rn(ox, oy);
            __half2 o23 = __floats2half2_rn(oz, ow);
            uint2 pk; pk.x = *(unsigned*)&o01; pk.y = *(unsigned*)&o23;
            *(uint2*)(so + ((size_t)b * CQKV + oc) * HLEN + itile * 16 + lh * 4) = pk;
            s0  += ox + oy + oz + ow;
            ss0 += ox * ox + oy * oy + oz * oz + ow * ow;
        }
        s0  += __shfl_xor(s0, 16);  s0  += __shfl_xor(s0, 32);
        ss0 += __shfl_xor(ss0, 16); ss0 += __shfl_xor(ss0, 32);
        if (lh == 0) {
            atomicAdd(&accL[2 * lr][0], s0);
            atomicAdd(&accL[2 * lr][1], ss0);
        }
    }
    __syncthreads();
    if (t < 32) {
        int o = g * 32 + t;
        atomicAdd(&accF[(size_t)o * 2 + 0], (double)accL[t][0]);
        atomicAdd(&accF[(size_t)o * 2 + 1], (double)accL[t][1]);
    }
}

// ---------------------------------------------------------------------------
// Final affine + pair-sum + transpose (f16 in, f32 out)
// ---------------------------------------------------------------------------
__global__ __launch_bounds__(256) void k_out(const unsigned short* __restrict__ so,
                                             const float* __restrict__ scale,
                                             const float* __restrict__ shift,
                                             float* __restrict__ out) {
    int b = blockIdx.x, n = b >> 6, wi = b & 63;
    int t = threadIdx.x;
    int h4  = (t & 31) << 2;
    int oc0 = (t >> 5) << 4;
    for (int k = 0; k < 16; ++k) {
        int oc = oc0 + k;
        uint2 u0 = *(const uint2*)(so + ((size_t)b * CQKV + 2 * oc) * HLEN + h4);
        uint2 u1 = *(const uint2*)(so + ((size_t)b * CQKV + 2 * oc + 1) * HLEN + h4);
        __half2 a0 = *(__half2*)&u0.x, a1 = *(__half2*)&u0.y;
        __half2 b0 = *(__half2*)&u1.x, b1 = *(__half2*)&u1.y;
        float s0 = scale[2 * oc], f0 = shift[2 * oc];
        float s1 = scale[2 * oc + 1], f1 = shift[2 * oc + 1];
        float4 o4;
        o4.x = fmaf(__low2float(a0),  s0, f0) + fmaf(__low2float(b0),  s1, f1);
        o4.y = fmaf(__high2float(a0), s0, f0) + fmaf(__high2float(b0), s1, f1);
        o4.z = fmaf(__low2float(a1),  s0, f0) + fmaf(__low2float(b1),  s1, f1);
        o4.w = fmaf(__high2float(a1), s0, f0) + fmaf(__high2float(b1), s1, f1);
        *(float4*)(out + (((size_t)n * 128 + oc) * 64 + wi) * HLEN + h4) = o4;
    }
}

extern "C" void kernel_launch(void* const* d_in, const int* in_sizes, int n_in,
                              void* d_out, int out_size, void* d_ws, size_t ws_size,
                              hipStream_t stream) {
    const float* x   = (const float*)d_in[0];
    const float* w   = (const float*)d_in[1];
    const float* g1  = (const float*)d_in[2];
    const float* b1  = (const float*)d_in[3];
    const float* g2  = (const float*)d_in[4];
    const float* b2  = (const float*)d_in[5];
    const float* gs  = (const float*)d_in[6];
    const float* bs  = (const float*)d_in[7];
    const float* go  = (const float*)d_in[8];
    const float* bo  = (const float*)d_in[9];
    const float* rel = (const float*)d_in[10];
    float* out = (float*)d_out;

    unsigned short* qkv = (unsigned short*)d_ws;        // 16,777,216 f16
    unsigned short* so  = qkv + (size_t)16777216;       // 16,777,216 f16
    double* accA   = (double*)(so + (size_t)16777216);  // 512 d
    double* accS   = accA + 512;                        // 48 d
    double* accF   = accS + 48;                         // 512 d
    float*  scaleA = (float*)(accF + 512);
    float*  shiftA = scaleA + 256;
    float*  scaleS = shiftA + 256;                      // 24
    float*  shiftS = scaleS + 24;
    float*  scaleF = shiftS + 24;                       // 256
    float*  shiftF = scaleF + 256;
    float*  Rq     = shiftF + 256;                      // 1024
    float*  Rk     = Rq + 1024;                         // 1024
    float*  TqT    = Rk + 1024;                         // 8192
    float*  TkT    = TqT + 8192;                        // 8192

    hipMemsetAsync(accA, 0, (512 + 48 + 512) * sizeof(double), stream);

    k_qkv<<<1024, 256, 0, stream>>>(x, w, qkv, accA);
    k_tables<<<128, 128, 0, stream>>>(rel, Rq, Rk, TqT, TkT);
    k_finA<<<1, 256, 0, stream>>>(accA, g1, g2, b2, scaleA, shiftA);
    k_gram<<<4096, 256, 0, stream>>>(qkv, scaleA, shiftA, Rq, Rk, TqT, TkT, accS);
    k_sfin<<<1, 32, 0, stream>>>(accS, gs, bs, scaleS, shiftS);
    k_attn<<<4096, 256, 0, stream>>>(qkv, scaleA, shiftA, rel, scaleS, shiftS, so, accF);
    k_finF<<<1, 256, 0, stream>>>(accF, go, bo, scaleF, shiftF);
    k_out<<<512, 256, 0, stream>>>(so, scaleF, shiftF, out);
}